// Round 6
// baseline (45842.288 us; speedup 1.0000x reference)
//
#include <hip/hip_runtime.h>
#include <cmath>

typedef unsigned short u16;
typedef __attribute__((ext_vector_type(8))) short short8;
typedef __attribute__((ext_vector_type(4))) float floatx4;

#define DEVI __device__ __forceinline__

constexpr int cV = 32000, cE = 512, cT = 64, cH = 1024, cZ = 128, cB = 64, cPAD = 31999, cTP1 = 65;
constexpr long long LOGP_SZ = 133120000LL;           // B*(T+1)*V  (f32 elements)
constexpr long long AMAT_OFF = 130990080LL;          // LOGP_SZ - 4160*1024/2  (f32 offset of bf16 Amat tail)

DEVI u16 f2b(float f) {
  unsigned u = __float_as_uint(f);
  unsigned r = u + 0x7FFFu + ((u >> 16) & 1u);
  return (u16)(r >> 16);
}
DEVI float sigm(float x) { return 1.f / (1.f + expf(-x)); }

// dot( f32 weight row , f32 LDS vector ), 4 accumulate chains
DEVI float dot_wf(const float* __restrict__ w, const float* __restrict__ s, int K) {
  float a0 = 0.f, a1 = 0.f, a2 = 0.f, a3 = 0.f;
#pragma unroll 4
  for (int k = 0; k < K; k += 8) {
    float4 p = *(const float4*)(w + k);
    float4 q = *(const float4*)(w + k + 4);
    a0 = fmaf(s[k + 0], p.x, a0);
    a1 = fmaf(s[k + 1], p.y, a1);
    a2 = fmaf(s[k + 2], p.z, a2);
    a3 = fmaf(s[k + 3], p.w, a3);
    a0 = fmaf(s[k + 4], q.x, a0);
    a1 = fmaf(s[k + 5], q.y, a1);
    a2 = fmaf(s[k + 6], q.z, a2);
    a3 = fmaf(s[k + 7], q.w, a3);
  }
  return (a0 + a1) + (a2 + a3);
}

// one weight row dotted against 4 batch vectors (LDS), accumulating into acc[4]
DEVI void dot4x(const float* __restrict__ w, const float* s0, const float* s1,
                const float* s2, const float* s3, int K, float acc[4]) {
  for (int k = 0; k < K; k += 8) {
    float4 wa = *(const float4*)(w + k);
    float4 wb = *(const float4*)(w + k + 4);
#define TERM(S, A)                                                     \
  {                                                                    \
    float4 xa = *(const float4*)(S + k);                               \
    float4 xb = *(const float4*)(S + k + 4);                           \
    A = fmaf(wa.x, xa.x, A); A = fmaf(wa.y, xa.y, A);                  \
    A = fmaf(wa.z, xa.z, A); A = fmaf(wa.w, xa.w, A);                  \
    A = fmaf(wb.x, xb.x, A); A = fmaf(wb.y, xb.y, A);                  \
    A = fmaf(wb.z, xb.z, A); A = fmaf(wb.w, xb.w, A);                  \
  }
    TERM(s0, acc[0]) TERM(s1, acc[1]) TERM(s2, acc[2]) TERM(s3, acc[3])
#undef TERM
  }
}

// load 8 f32 weights as one bf16 MFMA fragment (on-the-fly convert)
DEVI short8 ldfragW(const float* __restrict__ p) {
  float4 x = *(const float4*)p, y = *(const float4*)(p + 4);
  short8 r;
  r[0] = (short)f2b(x.x); r[1] = (short)f2b(x.y);
  r[2] = (short)f2b(x.z); r[3] = (short)f2b(x.w);
  r[4] = (short)f2b(y.x); r[5] = (short)f2b(y.y);
  r[6] = (short)f2b(y.z); r[7] = (short)f2b(y.w);
  return r;
}

__global__ __launch_bounds__(256) void k_zero(float* p, int n) {
  int i = blockIdx.x * 256 + threadIdx.x;
  if (i < n) p[i] = 0.f;
}

// ---------------- encoder LSTM step, 4 batch elems per block ----------------
__global__ __launch_bounds__(256) void k_enc_step(
    const int* __restrict__ enc_input, const float* __restrict__ emb,
    const float* __restrict__ Wih, const float* __restrict__ Whh,
    const float* __restrict__ bih, const float* __restrict__ bhh,
    const float* __restrict__ h_in, float* __restrict__ h_out,
    float* __restrict__ c, float* __restrict__ enc_out, int t) {
  __shared__ float xs[4][cE];
  __shared__ float hs[4][cH];
  int bg = blockIdx.x >> 2;   // 0..15
  int jb = blockIdx.x & 3;    // 0..3
  int tid = threadIdx.x;
#pragma unroll
  for (int bb = 0; bb < 4; bb++) {
    int b = bg * 4 + bb;
    const float* xr = emb + (size_t)enc_input[b * cT + t] * cE;
    for (int k = tid; k < cE; k += 256) xs[bb][k] = xr[k];
    const float* hb = h_in + b * cH;
    for (int k = tid; k < cH; k += 256) hs[bb][k] = hb[k];
  }
  __syncthreads();
  int j = jb * 256 + tid;
  float g[4][4];
#pragma unroll
  for (int gi = 0; gi < 4; gi++) {
    int n = gi * cH + j;
    float base = bih[n] + bhh[n];
    float acc[4] = {base, base, base, base};
    dot4x(Wih + (size_t)n * cE, xs[0], xs[1], xs[2], xs[3], cE, acc);
    dot4x(Whh + (size_t)n * cH, hs[0], hs[1], hs[2], hs[3], cH, acc);
#pragma unroll
    for (int bb = 0; bb < 4; bb++) g[gi][bb] = acc[bb];
  }
#pragma unroll
  for (int bb = 0; bb < 4; bb++) {
    int b = bg * 4 + bb;
    int idx = b * cH + j;
    float cc = c[idx];
    cc = sigm(g[1][bb]) * cc + sigm(g[0][bb]) * tanhf(g[2][bb]);
    float hh = sigm(g[3][bb]) * tanhf(cc);
    c[idx] = cc;
    h_out[idx] = hh;
    enc_out[((size_t)b * cT + t) * cH + j] = hh;
  }
}

// ---------------- latent: mu/logvar (f32 outputs) ----------------
__global__ __launch_bounds__(256) void k_latent(
    const float* __restrict__ hT, const float* __restrict__ cT2,
    const float* __restrict__ W, const float* __restrict__ bias,
    float* __restrict__ mulv, float* __restrict__ outp) {
  __shared__ float s[2 * cH];
  int b = blockIdx.x;
  int n = threadIdx.x;
  for (int k = n; k < cH; k += 256) {
    s[k] = hT[b * cH + k];
    s[cH + k] = cT2[b * cH + k];
  }
  __syncthreads();
  float acc = bias[n] + dot_wf(W + (size_t)n * (2 * cH), s, 2 * cH);
  mulv[b * 256 + n] = acc;
  if (n < cZ)
    outp[LOGP_SZ + (size_t)b * cZ + n] = acc;
  else
    outp[LOGP_SZ + (size_t)cB * cZ + (size_t)b * cZ + (n - cZ)] = acc;
}

__global__ __launch_bounds__(256) void k_z(const float* __restrict__ mulv,
                                           const float* __restrict__ eps,
                                           float* __restrict__ z) {
  int i = blockIdx.x * 256 + threadIdx.x;
  if (i >= cB * cZ) return;
  int b = i >> 7, zi = i & 127;
  float mu = mulv[b * 256 + zi], lv = mulv[b * 256 + cZ + zi];
  z[i] = mu + expf(0.5f * lv) * eps[i];
}

// ---------------- decoder K1: pri net + attention ----------------
__global__ __launch_bounds__(256) void k_dec1(
    const float* __restrict__ h, const float* __restrict__ enc_out,
    const float* __restrict__ priW, const float* __restrict__ prib,
    const float* __restrict__ attnW, const float* __restrict__ attnb,
    const int* __restrict__ dec_input, const float* __restrict__ demb,
    const int* __restrict__ enc_input,
    float* __restrict__ pri, float* __restrict__ ctx, int t) {
  int tid = threadIdx.x;
  if (blockIdx.x < cB) {
    int b = blockIdx.x;
    __shared__ float hs[cH];
    for (int k = tid; k < cH; k += 256) hs[k] = h[b * cH + k];
    __syncthreads();
    float acc = prib[tid] + dot_wf(priW + (size_t)tid * cH, hs, cH);
    pri[b * 256 + tid] = acc;
  } else {
    int b = blockIdx.x - cB;
    __shared__ float xs[cE];
    __shared__ float hs2[cH];
    __shared__ float wat[cT];
    const float* xr = demb + (size_t)dec_input[b * cTP1 + t] * cE;
    for (int k = tid; k < cE; k += 256) xs[k] = xr[k];
    for (int k = tid; k < cH; k += 256) hs2[k] = h[b * cH + k];
    __syncthreads();
    if (tid < cT) {  // lanes 0..63 of wave 0
      const float* wr = attnW + (size_t)tid * (cE + cH);
      float sc = attnb[tid];
      sc += dot_wf(wr, xs, cE);
      sc += dot_wf(wr + cE, hs2, cH);
      if (enc_input[b * cT + tid] == cPAD) sc = -INFINITY;
      float m = sc;
#pragma unroll
      for (int off = 32; off >= 1; off >>= 1) m = fmaxf(m, __shfl_xor(m, off));
      float p = expf(sc - m);
      float ssum = p;
#pragma unroll
      for (int off = 32; off >= 1; off >>= 1) ssum += __shfl_xor(ssum, off);
      wat[tid] = p / ssum;
    }
    __syncthreads();
#pragma unroll
    for (int jj = 0; jj < 4; jj++) {
      int j = jj * 256 + tid;
      float a = 0.f;
      const float* e = enc_out + (size_t)b * cT * cH + j;
#pragma unroll 8
      for (int t2 = 0; t2 < cT; t2++) a += wat[t2] * e[(size_t)t2 * cH];
      ctx[b * cH + j] = a;
    }
  }
}

// ---------------- decoder K2: inf net + aux_mu ----------------
__global__ __launch_bounds__(256) void k_dec2(
    const float* __restrict__ h, const float* __restrict__ ctx,
    const float* __restrict__ infW, const float* __restrict__ infb,
    const float* __restrict__ pri,
    const float* __restrict__ auxW, const float* __restrict__ auxb,
    float* __restrict__ infv, float* __restrict__ auxmu) {
  int tid = threadIdx.x;
  if (blockIdx.x < cB) {
    int b = blockIdx.x;
    __shared__ float s[2 * cH];
    for (int k = tid; k < cH; k += 256) {
      s[k] = h[b * cH + k];
      s[cH + k] = ctx[b * cH + k];
    }
    __syncthreads();
    float acc = infb[tid] + dot_wf(infW + (size_t)tid * (2 * cH), s, 2 * cH);
    infv[b * 256 + tid] = acc;
  } else {
    int q = blockIdx.x - cB;  // 0..255
    int b = q >> 2;
    int j = (q & 3) * 256 + tid;
    __shared__ float zs[cZ];
    if (tid < cZ) zs[tid] = pri[b * 256 + tid];  // z_step = pri_mu
    __syncthreads();
    float acc = auxb[j] + dot_wf(auxW + (size_t)j * cZ, zs, cZ);
    auxmu[b * cH + j] = acc;
  }
}

// ---------------- decoder K3: combine GEMM (4 b / block) + kld/aux reductions ----------------
__global__ __launch_bounds__(256) void k_dec3(
    const int* __restrict__ dec_input, const float* __restrict__ demb,
    const float* __restrict__ auxmu, const float* __restrict__ pri,
    const float* __restrict__ zvec, const float* __restrict__ combW,
    const float* __restrict__ combb, const float* __restrict__ ctx,
    const float* __restrict__ infv, const int* __restrict__ length,
    float* __restrict__ uvec, float* __restrict__ scal, int t) {
  int tid = threadIdx.x;
  if (blockIdx.x < 64) {
    int bg = blockIdx.x >> 2;   // 0..15
    int jb = blockIdx.x & 3;    // 0..3
    __shared__ float s[4][cE + cH + 2 * cZ];  // 4 x 1792 f32 = 28 KB
#pragma unroll
    for (int bb = 0; bb < 4; bb++) {
      int b = bg * 4 + bb;
      const float* xr = demb + (size_t)dec_input[b * cTP1 + t] * cE;
      for (int k = tid; k < cE; k += 256) s[bb][k] = xr[k];
      for (int k = tid; k < cH; k += 256) s[bb][cE + k] = auxmu[b * cH + k];
      if (tid < cZ) {
        s[bb][cE + cH + tid] = pri[b * 256 + tid];        // z_step = pri_mu
        s[bb][cE + cH + cZ + tid] = zvec[b * cZ + tid];   // z
      }
    }
    __syncthreads();
    int j = jb * 256 + tid;
    float base = combb[j];
    float acc[4] = {base, base, base, base};
    dot4x(combW + (size_t)j * (cE + cH + 2 * cZ), s[0], s[1], s[2], s[3],
          cE + cH + 2 * cZ, acc);
#pragma unroll
    for (int bb = 0; bb < 4; bb++) uvec[(bg * 4 + bb) * cH + j] = acc[bb];
  } else {
    int b = blockIdx.x - 64;
    float k1 = 0.f;
    if (tid < cZ) {
      float pm = pri[b * 256 + tid], plv = pri[b * 256 + cZ + tid];
      float im = infv[b * 256 + tid], ilv = infv[b * 256 + cZ + tid];
      float d = im - pm;
      k1 = plv - ilv + expf(ilv - plv) + d * d * expf(-plv) - 1.f;
    }
    float a1 = 0.f;
    for (int j = tid; j < cH; j += 256) {
      float d = ctx[b * cH + j] - auxmu[b * cH + j];
      a1 += d * d;
    }
    __shared__ float r1[256], r2[256];
    r1[tid] = k1;
    r2[tid] = a1;
    __syncthreads();
    for (int sft = 128; sft > 0; sft >>= 1) {
      if (tid < sft) {
        r1[tid] += r1[tid + sft];
        r2[tid] += r2[tid + sft];
      }
      __syncthreads();
    }
    if (tid == 0) {
      if (length[b] + 1 > t) atomicAdd(&scal[0], 0.5f * r1[0]);
      atomicAdd(&scal[1], r2[0]);
    }
  }
}

// ---------------- decoder LSTM cell, 4 batch elems per block ----------------
__global__ __launch_bounds__(256) void k_dec_cell(
    const float* __restrict__ Wih, const float* __restrict__ Whh,
    const float* __restrict__ bih, const float* __restrict__ bhh,
    const float* __restrict__ u, const float* __restrict__ h_in,
    float* __restrict__ h_out, float* __restrict__ c,
    u16* __restrict__ Amat, int t) {
  __shared__ float us[4][cH];
  __shared__ float hs[4][cH];
  int bg = blockIdx.x >> 2;
  int jb = blockIdx.x & 3;
  int tid = threadIdx.x;
#pragma unroll
  for (int bb = 0; bb < 4; bb++) {
    int b = bg * 4 + bb;
    for (int k = tid; k < cH; k += 256) {
      us[bb][k] = u[b * cH + k];
      hs[bb][k] = h_in[b * cH + k];
    }
  }
  __syncthreads();
  int j = jb * 256 + tid;
  float g[4][4];
#pragma unroll
  for (int gi = 0; gi < 4; gi++) {
    int n = gi * cH + j;
    float base = bih[n] + bhh[n];
    float acc[4] = {base, base, base, base};
    dot4x(Wih + (size_t)n * cH, us[0], us[1], us[2], us[3], cH, acc);
    dot4x(Whh + (size_t)n * cH, hs[0], hs[1], hs[2], hs[3], cH, acc);
#pragma unroll
    for (int bb = 0; bb < 4; bb++) g[gi][bb] = acc[bb];
  }
#pragma unroll
  for (int bb = 0; bb < 4; bb++) {
    int b = bg * 4 + bb;
    int idx = b * cH + j;
    float cc = c[idx];
    cc = sigm(g[1][bb]) * cc + sigm(g[0][bb]) * tanhf(g[2][bb]);
    float hh = sigm(g[3][bb]) * tanhf(cc);
    c[idx] = cc;
    h_out[idx] = hh;
    Amat[((size_t)b * cTP1 + t) * cH + j] = f2b(hh);
  }
}

// copy Amat rows [4032,4160) (256 KB) from the d_out tail into d_ws
__global__ __launch_bounds__(256) void k_cpyA(const u16* __restrict__ src,
                                              u16* __restrict__ dst) {
  int i = blockIdx.x * 256 + threadIdx.x;  // 16384 threads, uint4 each
  ((uint4*)dst)[i] = ((const uint4*)(src + (size_t)4032 * cH))[i];
}

// ---- output projection GEMM: logit[4160,32000] = A(bf16) * out_W^T + b, f32 store ----
// BM=128 x BN=64 per block; 4 waves (2 wm x 2 wn); wave computes 64 rows x 32 cols.
__global__ __launch_bounds__(256) void k_logit(
    const u16* __restrict__ A, int aBase, int msBase, int mLo, int mHi,
    const float* __restrict__ Wv, const float* __restrict__ bias,
    float* __restrict__ outp) {
  int blk = blockIdx.x;
  int nb = blk % 500, mb = blk / 500;
  int wave = threadIdx.x >> 6, lane = threadIdx.x & 63;
  int wm = wave >> 1, wn = wave & 1;
  int ms = msBase + mb * 128 + wm * 64;
  int ns = nb * 64 + wn * 32;
  int lr = lane & 15, kg = lane >> 4;
  const short8* aP[4];
#pragma unroll
  for (int mi = 0; mi < 4; mi++) {
    int row = ms + mi * 16 + lr;
    aP[mi] = (const short8*)(A + (size_t)(row - aBase) * cH + kg * 8);
  }
  const float* bP0 = Wv + (size_t)(ns + lr) * cH + kg * 8;
  const float* bP1 = Wv + (size_t)(ns + 16 + lr) * cH + kg * 8;
  floatx4 acc[4][2];
#pragma unroll
  for (int mi = 0; mi < 4; mi++)
#pragma unroll
    for (int ni = 0; ni < 2; ni++) acc[mi][ni] = (floatx4){0.f, 0.f, 0.f, 0.f};
  for (int k0 = 0; k0 < cH; k0 += 32) {
    short8 bv0 = ldfragW(bP0 + k0);
    short8 bv1 = ldfragW(bP1 + k0);
#pragma unroll
    for (int mi = 0; mi < 4; mi++) {
      short8 av = aP[mi][k0 >> 3];
      acc[mi][0] = __builtin_amdgcn_mfma_f32_16x16x32_bf16(av, bv0, acc[mi][0], 0, 0, 0);
      acc[mi][1] = __builtin_amdgcn_mfma_f32_16x16x32_bf16(av, bv1, acc[mi][1], 0, 0, 0);
    }
  }
#pragma unroll
  for (int mi = 0; mi < 4; mi++) {
#pragma unroll
    for (int ni = 0; ni < 2; ni++) {
      int n = ns + ni * 16 + lr;
      float bb = bias[n];
#pragma unroll
      for (int jj = 0; jj < 4; jj++) {
        int m = ms + mi * 16 + kg * 4 + jj;
        if (m >= mLo && m < mHi)
          outp[(size_t)m * cV + n] = acc[mi][ni][jj] + bb;
      }
    }
  }
}

// ---------------- row log-softmax over V, f32 in-place, 3 global passes ----------------
__global__ __launch_bounds__(256) void k_lsm(float* __restrict__ outp) {
  __shared__ float wred[4];
  __shared__ float bval;
  int m = blockIdx.x;
  int tid = threadIdx.x, lane = tid & 63, wid = tid >> 6;
  float* rp = outp + (size_t)m * cV;
  float mx = -INFINITY;
  for (int n = tid; n < cV; n += 256) mx = fmaxf(mx, rp[n]);
#pragma unroll
  for (int off = 32; off >= 1; off >>= 1) mx = fmaxf(mx, __shfl_xor(mx, off));
  if (lane == 0) wred[wid] = mx;
  __syncthreads();
  if (tid == 0) bval = fmaxf(fmaxf(wred[0], wred[1]), fmaxf(wred[2], wred[3]));
  __syncthreads();
  mx = bval;
  float s = 0.f;
  for (int n = tid; n < cV; n += 256) s += expf(rp[n] - mx);
#pragma unroll
  for (int off = 32; off >= 1; off >>= 1) s += __shfl_xor(s, off);
  __syncthreads();  // tid0's earlier wred reads complete before rewrite
  if (lane == 0) wred[wid] = s;
  __syncthreads();
  if (tid == 0) bval = mx + logf(wred[0] + wred[1] + wred[2] + wred[3]);
  __syncthreads();
  float lz = bval;
  for (int n = tid; n < cV; n += 256) rp[n] = rp[n] - lz;
}

__global__ void k_scal(const float* __restrict__ scal, float* __restrict__ outp) {
  if (threadIdx.x == 0) {
    outp[LOGP_SZ + 2 * cB * cZ] = scal[0];
    outp[LOGP_SZ + 2 * cB * cZ + 1] = scal[1];
  }
}

extern "C" void kernel_launch(void* const* d_in, const int* in_sizes, int n_in,
                              void* d_out, int out_size, void* d_ws, size_t ws_size,
                              hipStream_t stream) {
  (void)in_sizes; (void)n_in; (void)out_size; (void)ws_size;
  const int* enc_input  = (const int*)d_in[0];
  const int* dec_input  = (const int*)d_in[1];
  const int* length     = (const int*)d_in[2];
  const float* eps      = (const float*)d_in[3];
  const float* enc_emb  = (const float*)d_in[4];
  const float* enc_Wih  = (const float*)d_in[5];
  const float* enc_Whh  = (const float*)d_in[6];
  const float* enc_bih  = (const float*)d_in[7];
  const float* enc_bhh  = (const float*)d_in[8];
  const float* latent_W = (const float*)d_in[9];
  const float* latent_b = (const float*)d_in[10];
  const float* dec_emb  = (const float*)d_in[11];
  const float* attn_W   = (const float*)d_in[12];
  const float* attn_b   = (const float*)d_in[13];
  const float* comb_W   = (const float*)d_in[14];
  const float* comb_b   = (const float*)d_in[15];
  const float* dec_Wih  = (const float*)d_in[16];
  const float* dec_Whh  = (const float*)d_in[17];
  const float* dec_bih  = (const float*)d_in[18];
  const float* dec_bhh  = (const float*)d_in[19];
  const float* pri_W    = (const float*)d_in[20];
  const float* pri_b    = (const float*)d_in[21];
  const float* inf_W    = (const float*)d_in[22];
  const float* inf_b    = (const float*)d_in[23];
  const float* aux_W    = (const float*)d_in[24];
  const float* aux_b    = (const float*)d_in[25];
  const float* out_W    = (const float*)d_in[26];
  const float* out_b    = (const float*)d_in[27];
  float* outp = (float*)d_out;   // OUTPUT IS FLOAT32

  // ---- scratch placement ----
  // Low logp region (rows < 146): recurrent state. Dead before k_logit runs.
  float* outF = outp;
  size_t off = 0;
  float* enc_out = outF + off; off += (size_t)cB * cT * cH;   // 4,194,304
  float* hA   = outF + off; off += cB * cH;
  float* hB   = outF + off; off += cB * cH;
  float* cbuf = outF + off; off += cB * cH;
  float* scal = outF + off; off += 4;
  float* mulv = outF + off; off += cB * 256;
  float* zvec = outF + off; off += cB * cZ;
  float* pri  = outF + off; off += cB * 256;
  float* ctx  = outF + off; off += cB * cH;
  float* infv = outF + off; off += cB * 256;
  float* auxmu= outF + off; off += cB * cH;
  float* uvec = outF + off; off += cB * cH;      // total 4,644,868 f32 (rows < 146)
  // Amat (bf16) in the logp TAIL (f32 rows >= 4093.4). k_logit split handles overlap.
  u16* Amat = (u16*)(outF + AMAT_OFF);
  // d_ws: 256 KB copy of Amat rows [4032,4160) for k_logit launch B.
  u16* wsA = (u16*)d_ws;

  // zero hA,hB,cbuf,scal (contiguous)
  k_zero<<<(3 * cB * cH + 4 + 255) / 256, 256, 0, stream>>>(hA, 3 * cB * cH + 4);

  // ---- encoder ----
  for (int t = 0; t < cT; t++) {
    const float* hin = (t & 1) ? hB : hA;
    float* hout = (t & 1) ? hA : hB;
    k_enc_step<<<64, 256, 0, stream>>>(enc_input, enc_emb, enc_Wih, enc_Whh,
                                       enc_bih, enc_bhh, hin, hout, cbuf, enc_out, t);
  }
  // h_T in hA (64 steps), c_T in cbuf
  k_latent<<<cB, 256, 0, stream>>>(hA, cbuf, latent_W, latent_b, mulv, outp);
  k_z<<<(cB * cZ + 255) / 256, 256, 0, stream>>>(mulv, eps, zvec);

  // re-zero h/c for decoder (keep scal accumulating from zero)
  k_zero<<<(3 * cB * cH + 255) / 256, 256, 0, stream>>>(hA, 3 * cB * cH);

  // ---- decoder ----
  for (int t = 0; t < cTP1; t++) {
    const float* hin = (t & 1) ? hB : hA;
    float* hout = (t & 1) ? hA : hB;
    k_dec1<<<2 * cB, 256, 0, stream>>>(hin, enc_out, pri_W, pri_b, attn_W, attn_b,
                                       dec_input, dec_emb, enc_input, pri, ctx, t);
    k_dec2<<<cB + 256, 256, 0, stream>>>(hin, ctx, inf_W, inf_b, pri, aux_W, aux_b,
                                         infv, auxmu);
    k_dec3<<<64 + cB, 256, 0, stream>>>(dec_input, dec_emb, auxmu, pri, zvec,
                                        comb_W, comb_b, ctx, infv, length,
                                        uvec, scal, t);
    k_dec_cell<<<64, 256, 0, stream>>>(dec_Wih, dec_Whh, dec_bih, dec_bhh,
                                       uvec, hin, hout, cbuf, Amat, t);
  }

  // kld/aux scalars BEFORE k_logit (scal lives in the logp scratch region)
  k_scal<<<1, 64, 0, stream>>>(scal, outp);

  // ---- output projection + log-softmax (f32) ----
  // copy tail A-rows that k_logit launch B both reads and overwrites
  k_cpyA<<<64, 256, 0, stream>>>(Amat, wsA);
  // launch A: rows [0,4096) computed, stores masked to m < 4093 (reads tail, safe)
  k_logit<<<32 * 500, 256, 0, stream>>>(Amat, 0, 0, 0, 4093, out_W, out_b, outp);
  // launch B: rows [4032,4160), A from ws copy, stores masked to m >= 4093
  k_logit<<<500, 256, 0, stream>>>(wsA, 4032, 4032, 4093, 4160, out_W, out_b, outp);
  k_lsm<<<cB * cTP1, 256, 0, stream>>>(outp);
}

// Round 7
// 11534.608 us; speedup vs baseline: 3.9743x; 3.9743x over previous
//
#include <hip/hip_runtime.h>
#include <hip/hip_bf16.h>
#include <cmath>

typedef unsigned short u16;
typedef __attribute__((ext_vector_type(8))) short short8;
typedef __attribute__((ext_vector_type(4))) float floatx4;

#define DEVI __device__ __forceinline__

constexpr int cV = 32000, cE = 512, cT = 64, cH = 1024, cZ = 128, cB = 64, cPAD = 31999, cTP1 = 65;
constexpr long long LOGP_SZ = 133120000LL;   // B*(T+1)*V f32 elems
constexpr long long AMAT_OFF = 130990080LL;  // LOGP_SZ - 4160*1024/2

DEVI float b2f(u16 u) { return __uint_as_float(((unsigned)u) << 16); }
DEVI u16 f2b(float f) {  // RNE scalar (cold paths)
  unsigned u = __float_as_uint(f);
  unsigned r = u + 0x7FFFu + ((u >> 16) & 1u);
  return (u16)(r >> 16);
}
DEVI unsigned pk2(float lo, float hi) {  // packed cvt: 1 VALU op
  __hip_bfloat162 t = __float22bfloat162_rn(make_float2(lo, hi));
  return *reinterpret_cast<unsigned*>(&t);
}
DEVI float sigm(float x) { return 1.f / (1.f + expf(-x)); }

// dot( bf16 weight row , f32 vector ), f32 accumulate, 4 chains
DEVI float dot_wb(const u16* __restrict__ w, const float* __restrict__ s, int K) {
  float a0 = 0.f, a1 = 0.f, a2 = 0.f, a3 = 0.f;
  const uint4* w4 = (const uint4*)w;
#pragma unroll 4
  for (int k = 0; k < K; k += 8) {
    uint4 q = w4[k >> 3];
    a0 = fmaf(s[k + 0], __uint_as_float(q.x << 16), a0);
    a1 = fmaf(s[k + 1], __uint_as_float(q.x & 0xFFFF0000u), a1);
    a2 = fmaf(s[k + 2], __uint_as_float(q.y << 16), a2);
    a3 = fmaf(s[k + 3], __uint_as_float(q.y & 0xFFFF0000u), a3);
    a0 = fmaf(s[k + 4], __uint_as_float(q.z << 16), a0);
    a1 = fmaf(s[k + 5], __uint_as_float(q.z & 0xFFFF0000u), a1);
    a2 = fmaf(s[k + 6], __uint_as_float(q.w << 16), a2);
    a3 = fmaf(s[k + 7], __uint_as_float(q.w & 0xFFFF0000u), a3);
  }
  return (a0 + a1) + (a2 + a3);
}

// dot( f32 weight row , f32 vector )
DEVI float dot_wf(const float* __restrict__ w, const float* __restrict__ s, int K) {
  float a0 = 0.f, a1 = 0.f, a2 = 0.f, a3 = 0.f;
#pragma unroll 4
  for (int k = 0; k < K; k += 8) {
    float4 p = *(const float4*)(w + k);
    float4 q = *(const float4*)(w + k + 4);
    a0 = fmaf(s[k + 0], p.x, a0); a1 = fmaf(s[k + 1], p.y, a1);
    a2 = fmaf(s[k + 2], p.z, a2); a3 = fmaf(s[k + 3], p.w, a3);
    a0 = fmaf(s[k + 4], q.x, a0); a1 = fmaf(s[k + 5], q.y, a1);
    a2 = fmaf(s[k + 6], q.z, a2); a3 = fmaf(s[k + 7], q.w, a3);
  }
  return (a0 + a1) + (a2 + a3);
}

DEVI short8 ldfragW(const float* __restrict__ p) {  // 8 f32 -> bf16 frag via cvt_pk
  float4 x = *(const float4*)p, y = *(const float4*)(p + 4);
  union { unsigned u[4]; short8 s; } r;
  r.u[0] = pk2(x.x, x.y); r.u[1] = pk2(x.z, x.w);
  r.u[2] = pk2(y.x, y.y); r.u[3] = pk2(y.z, y.w);
  return r.s;
}

__global__ __launch_bounds__(256) void k_zero(float* p, int n) {
  int i = blockIdx.x * 256 + threadIdx.x;
  if (i < n) p[i] = 0.f;
}

// f32 -> bf16 flat convert
__global__ __launch_bounds__(256) void k_cvt(const float* __restrict__ in,
                                             u16* __restrict__ outp, int n) {
  int stride = gridDim.x * 256 * 4;
  for (int i = (blockIdx.x * 256 + threadIdx.x) * 4; i < n; i += stride) {
    float4 v = *(const float4*)(in + i);
    ushort4 r;
    r.x = f2b(v.x); r.y = f2b(v.y); r.z = f2b(v.z); r.w = f2b(v.w);
    *(ushort4*)(outp + i) = r;
  }
}

// permuted LSTM weight prep: Wp[n'=j*4+g][0:K1]=Wih[g*1024+j], [K1:K1+1024]=Whh
__global__ __launch_bounds__(256) void k_prep_lstm(
    const float* __restrict__ Wih, const float* __restrict__ Whh,
    const float* __restrict__ bih, const float* __restrict__ bhh,
    int K1, u16* __restrict__ Wp, float* __restrict__ biasp) {
  int np = blockIdx.x;  // 0..4095
  int j = np >> 2, g = np & 3;
  int src = g * cH + j;
  int ldb = K1 + cH;
  const float* wi = Wih + (size_t)src * K1;
  const float* wh = Whh + (size_t)src * cH;
  u16* dst = Wp + (size_t)np * ldb;
  int tid = threadIdx.x;
  for (int k = tid; k < K1; k += 256) dst[k] = f2b(wi[k]);
  for (int k = tid; k < cH; k += 256) dst[K1 + k] = f2b(wh[k]);
  if (tid == 0) biasp[np] = bih[src] + bhh[src];
}

// gather embeddings -> bf16, layout [t][b][512]
__global__ __launch_bounds__(256) void k_gather(
    const int* __restrict__ tok, const float* __restrict__ emb,
    u16* __restrict__ dst, int Tlen) {
  int r = blockIdx.x;          // t*64 + b
  int t = r >> 6, b = r & 63;
  const float* src = emb + (size_t)tok[b * Tlen + t] * cE;
  u16* d = dst + (size_t)r * cE;
  int tid = threadIdx.x;
  for (int k = tid; k < cE; k += 256) d[k] = f2b(src[k]);
}

// ---- fused LSTM step: gates GEMM (MFMA, permuted bf16 weights) + cell math ----
// grid 256 x 64thr; block nb covers n' in [nb*16, nb*16+16) => j in [nb*4, nb*4+4)
template <int K1, int ROWMUL>
__global__ __launch_bounds__(64) void k_cell(
    const u16* __restrict__ A1,      // [64][K1] bf16 (x_t or u)
    const u16* __restrict__ A2,      // [64][1024] bf16 (h_cur)
    const u16* __restrict__ Wp,      // [4096][K1+1024] bf16 permuted
    const float* __restrict__ biasp, // [4096]
    float* __restrict__ c,           // [64][1024] f32
    u16* __restrict__ Hnext,         // [64][1024] bf16
    u16* __restrict__ out2,          // enc_out (ROWMUL=64) or Amat (65)
    int t) {
  constexpr int LDB = K1 + cH;
  int lane = threadIdx.x;
  int nb = blockIdx.x;
  int lr = lane & 15, kg = lane >> 4;
  const u16* Bp = Wp + (size_t)(nb * 16 + lr) * LDB + kg * 8;
  floatx4 acc[4];
#pragma unroll
  for (int mf = 0; mf < 4; mf++) acc[mf] = (floatx4){0.f, 0.f, 0.f, 0.f};
#pragma unroll 4
  for (int ks = 0; ks < K1 / 32; ks++) {
    short8 bv = *(const short8*)(Bp + ks * 32);
#pragma unroll
    for (int mf = 0; mf < 4; mf++) {
      short8 av = *(const short8*)(A1 + (size_t)(mf * 16 + lr) * K1 + ks * 32 + kg * 8);
      acc[mf] = __builtin_amdgcn_mfma_f32_16x16x32_bf16(av, bv, acc[mf], 0, 0, 0);
    }
  }
  const u16* Bp2 = Bp + K1;
#pragma unroll 4
  for (int ks = 0; ks < 32; ks++) {
    short8 bv = *(const short8*)(Bp2 + ks * 32);
#pragma unroll
    for (int mf = 0; mf < 4; mf++) {
      short8 av = *(const short8*)(A2 + (size_t)(mf * 16 + lr) * cH + ks * 32 + kg * 8);
      acc[mf] = __builtin_amdgcn_mfma_f32_16x16x32_bf16(av, bv, acc[mf], 0, 0, 0);
    }
  }
  // epilogue: LDS transpose (col = n' within block, row = batch) + cell math
  __shared__ float lds[16][65];
  float bs = biasp[nb * 16 + lr];
#pragma unroll
  for (int mf = 0; mf < 4; mf++)
#pragma unroll
    for (int jj = 0; jj < 4; jj++)
      lds[lr][mf * 16 + kg * 4 + jj] = acc[mf][jj] + bs;
  __syncthreads();
#pragma unroll
  for (int p = 0; p < 4; p++) {
    int idx = lane + p * 64;      // 0..255 cells: 4 j x 64 b
    int b = idx & 63, a = idx >> 6;
    int j = nb * 4 + a;
    float gi = lds[4 * a + 0][b];
    float gf = lds[4 * a + 1][b];
    float gg = lds[4 * a + 2][b];
    float go = lds[4 * a + 3][b];
    int ci = b * cH + j;
    float cc = c[ci];
    cc = sigm(gf) * cc + sigm(gi) * tanhf(gg);
    float hh = sigm(go) * tanhf(cc);
    c[ci] = cc;
    u16 hb = f2b(hh);
    Hnext[ci] = hb;
    out2[((size_t)b * ROWMUL + t) * cH + j] = hb;
  }
}

// ---- comb GEMM: u[64,1024] = XU[64,1792] * Wc^T + comb_b ----
__global__ __launch_bounds__(64) void k_comb(
    const u16* __restrict__ XU, const u16* __restrict__ Wc,
    const float* __restrict__ bias, u16* __restrict__ Ubuf) {
  constexpr int K = cE + cH + 2 * cZ;  // 1792
  int lane = threadIdx.x;
  int nb = blockIdx.x;  // 0..63
  int lr = lane & 15, kg = lane >> 4;
  const u16* Bp = Wc + (size_t)(nb * 16 + lr) * K + kg * 8;
  floatx4 acc[4];
#pragma unroll
  for (int mf = 0; mf < 4; mf++) acc[mf] = (floatx4){0.f, 0.f, 0.f, 0.f};
#pragma unroll 4
  for (int ks = 0; ks < K / 32; ks++) {
    short8 bv = *(const short8*)(Bp + ks * 32);
#pragma unroll
    for (int mf = 0; mf < 4; mf++) {
      short8 av = *(const short8*)(XU + (size_t)(mf * 16 + lr) * K + ks * 32 + kg * 8);
      acc[mf] = __builtin_amdgcn_mfma_f32_16x16x32_bf16(av, bv, acc[mf], 0, 0, 0);
    }
  }
  int n = nb * 16 + lr;
  float bs = bias[n];
#pragma unroll
  for (int mf = 0; mf < 4; mf++)
#pragma unroll
    for (int jj = 0; jj < 4; jj++) {
      int m = mf * 16 + kg * 4 + jj;
      Ubuf[(size_t)m * cH + n] = f2b(acc[mf][jj] + bs);
    }
}

// ---- fused decoder mid: pri + attn + softmax + ctx + inf + aux + kld + aux_c + XU ----
__global__ __launch_bounds__(256) void k_mid(
    const u16* __restrict__ Hcur, const u16* __restrict__ Xdec,
    const u16* __restrict__ enc_out, const int* __restrict__ enc_input,
    const u16* __restrict__ wAttn, const float* __restrict__ attn_b,
    const u16* __restrict__ wPri, const float* __restrict__ pri_b,
    const u16* __restrict__ wInf, const float* __restrict__ inf_b,
    const u16* __restrict__ wAux, const float* __restrict__ aux_b,
    const int* __restrict__ length, u16* __restrict__ XU,
    float* __restrict__ scal, int t) {
  __shared__ float xh[cE + cH];   // x | h
  __shared__ float part[64][4];
  __shared__ float wat[cT];
  __shared__ float ctxs[cH];
  __shared__ float pris[256];
  __shared__ float infs[256];
  __shared__ float am[cH];
  __shared__ float red[256];
  int b = blockIdx.x, tid = threadIdx.x;
  // load x_t[b], h[b]
  const u16* xr = Xdec + ((size_t)t * cB + b) * cE;
  for (int k = tid; k < cE; k += 256) xh[k] = b2f(xr[k]);
  const u16* hr = Hcur + (size_t)b * cH;
  for (int k = tid; k < cH; k += 256) xh[cE + k] = b2f(hr[k]);
  __syncthreads();
  // attn partials (4 threads per t) + pri (1 thread per output)
  {
    int tt = tid & 63, q = tid >> 6;
    part[tt][q] = dot_wb(wAttn + (size_t)tt * 1536 + q * 384, xh + q * 384, 384);
  }
  pris[tid] = pri_b[tid] + dot_wb(wPri + (size_t)tid * cH, xh + cE, cH);
  __syncthreads();
  // softmax over 64 t (wave 0)
  if (tid < cT) {
    float sc = part[tid][0] + part[tid][1] + part[tid][2] + part[tid][3] + attn_b[tid];
    if (enc_input[b * cT + tid] == cPAD) sc = -INFINITY;
    float m = sc;
#pragma unroll
    for (int off = 32; off >= 1; off >>= 1) m = fmaxf(m, __shfl_xor(m, off));
    float p = expf(sc - m);
    float ssum = p;
#pragma unroll
    for (int off = 32; off >= 1; off >>= 1) ssum += __shfl_xor(ssum, off);
    wat[tid] = p / ssum;
  }
  __syncthreads();
  // ctx
#pragma unroll
  for (int p = 0; p < 4; p++) {
    int j = tid + p * 256;
    float s = 0.f;
    const u16* e = enc_out + (size_t)b * cT * cH + j;
#pragma unroll 8
    for (int t2 = 0; t2 < cT; t2++) s += wat[t2] * b2f(e[(size_t)t2 * cH]);
    ctxs[j] = s;
  }
  __syncthreads();
  // inf (1 thread per output): concat(h, ctx)
  {
    const u16* wr = wInf + (size_t)tid * (2 * cH);
    infs[tid] = inf_b[tid] + dot_wb(wr, xh + cE, cH) + dot_wb(wr + cH, ctxs, cH);
  }
  __syncthreads();
  // aux (4 outputs/thread) + XU staging
#pragma unroll
  for (int p = 0; p < 4; p++) {
    int j = tid + p * 256;
    float s = aux_b[j] + dot_wb(wAux + (size_t)j * cZ, pris, cZ);  // z_step = pri_mu
    am[j] = s;
    XU[(size_t)b * 1792 + cE + j] = f2b(s);
  }
  XU[(size_t)b * 1792 + tid] = xr[tid];              // x slice (bf16 copy)
  XU[(size_t)b * 1792 + 256 + tid] = xr[256 + tid];
  if (tid < cZ) XU[(size_t)b * 1792 + cE + cH + tid] = f2b(pris[tid]);  // pri_mu
  __syncthreads();
  // kld partial
  float r = 0.f;
  if (tid < cZ) {
    float pm = pris[tid], plv = pris[tid + cZ];
    float im = infs[tid], ilv = infs[tid + cZ];
    float d = im - pm;
    r = plv - ilv + expf(ilv - plv) + d * d * expf(-plv) - 1.f;
  }
  red[tid] = r;
  __syncthreads();
  for (int sft = 128; sft > 0; sft >>= 1) {
    if (tid < sft) red[tid] += red[tid + sft];
    __syncthreads();
  }
  if (tid == 0 && (length[b] + 1 > t)) atomicAdd(&scal[0], 0.5f * red[0]);
  __syncthreads();
  // aux_c partial
  float r2 = 0.f;
#pragma unroll
  for (int p = 0; p < 4; p++) {
    int j = tid + p * 256;
    float d = ctxs[j] - am[j];
    r2 += d * d;
  }
  red[tid] = r2;
  __syncthreads();
  for (int sft = 128; sft > 0; sft >>= 1) {
    if (tid < sft) red[tid] += red[tid + sft];
    __syncthreads();
  }
  if (tid == 0) atomicAdd(&scal[1], red[0]);
}

// ---- latent: mu/logvar (h bf16, c f32) ----
__global__ __launch_bounds__(256) void k_latent(
    const u16* __restrict__ hT, const float* __restrict__ cT2,
    const float* __restrict__ W, const float* __restrict__ bias,
    float* __restrict__ mulv, float* __restrict__ outp) {
  __shared__ float s[2 * cH];
  int b = blockIdx.x;
  int n = threadIdx.x;
  for (int k = n; k < cH; k += 256) {
    s[k] = b2f(hT[b * cH + k]);
    s[cH + k] = cT2[b * cH + k];
  }
  __syncthreads();
  float acc = bias[n] + dot_wf(W + (size_t)n * (2 * cH), s, 2 * cH);
  mulv[b * 256 + n] = acc;
  if (n < cZ)
    outp[LOGP_SZ + (size_t)b * cZ + n] = acc;
  else
    outp[LOGP_SZ + (size_t)cB * cZ + (size_t)b * cZ + (n - cZ)] = acc;
}

__global__ __launch_bounds__(256) void k_z(const float* __restrict__ mulv,
                                           const float* __restrict__ eps,
                                           u16* __restrict__ XU) {
  int i = blockIdx.x * 256 + threadIdx.x;
  if (i >= cB * cZ) return;
  int b = i >> 7, zi = i & 127;
  float mu = mulv[b * 256 + zi], lv = mulv[b * 256 + cZ + zi];
  float z = mu + expf(0.5f * lv) * eps[i];
  XU[(size_t)b * 1792 + cE + cH + cZ + zi] = f2b(z);
}

// copy Amat rows [4032,4160) (256 KB) into d_ws
__global__ __launch_bounds__(256) void k_cpyA(const u16* __restrict__ src,
                                              u16* __restrict__ dst) {
  int i = blockIdx.x * 256 + threadIdx.x;  // 16384 x uint4
  ((uint4*)dst)[i] = ((const uint4*)(src + (size_t)4032 * cH))[i];
}

// ---- output projection: logit[4160,32000] = A(bf16) * out_W^T + b (f32 stores) ----
__global__ __launch_bounds__(256) void k_logit(
    const u16* __restrict__ A, int aBase, int msBase, int mLo, int mHi,
    const float* __restrict__ Wv, const float* __restrict__ bias,
    float* __restrict__ outp) {
  int blk = blockIdx.x;
  int nb = blk % 500, mb = blk / 500;
  int wave = threadIdx.x >> 6, lane = threadIdx.x & 63;
  int wm = wave >> 1, wn = wave & 1;
  int ms = msBase + mb * 128 + wm * 64;
  int ns = nb * 64 + wn * 32;
  int lr = lane & 15, kg = lane >> 4;
  const short8* aP[4];
#pragma unroll
  for (int mi = 0; mi < 4; mi++) {
    int row = ms + mi * 16 + lr;
    if (row > cB * cTP1 - 1) row = cB * cTP1 - 1;
    aP[mi] = (const short8*)(A + (size_t)(row - aBase) * cH + kg * 8);
  }
  const float* bP0 = Wv + (size_t)(ns + lr) * cH + kg * 8;
  const float* bP1 = Wv + (size_t)(ns + 16 + lr) * cH + kg * 8;
  floatx4 acc[4][2];
#pragma unroll
  for (int mi = 0; mi < 4; mi++)
#pragma unroll
    for (int ni = 0; ni < 2; ni++) acc[mi][ni] = (floatx4){0.f, 0.f, 0.f, 0.f};
  for (int k0 = 0; k0 < cH; k0 += 32) {
    short8 bv0 = ldfragW(bP0 + k0);
    short8 bv1 = ldfragW(bP1 + k0);
#pragma unroll
    for (int mi = 0; mi < 4; mi++) {
      short8 av = aP[mi][k0 >> 3];
      acc[mi][0] = __builtin_amdgcn_mfma_f32_16x16x32_bf16(av, bv0, acc[mi][0], 0, 0, 0);
      acc[mi][1] = __builtin_amdgcn_mfma_f32_16x16x32_bf16(av, bv1, acc[mi][1], 0, 0, 0);
    }
  }
#pragma unroll
  for (int mi = 0; mi < 4; mi++) {
#pragma unroll
    for (int ni = 0; ni < 2; ni++) {
      int n = ns + ni * 16 + lr;
      float bb = bias[n];
#pragma unroll
      for (int jj = 0; jj < 4; jj++) {
        int m = ms + mi * 16 + kg * 4 + jj;
        if (m >= mLo && m < mHi)
          outp[(size_t)m * cV + n] = acc[mi][ni][jj] + bb;
      }
    }
  }
}

// ---- row log-softmax over V, f32 in-place ----
__global__ __launch_bounds__(256) void k_lsm(float* __restrict__ outp) {
  __shared__ float wred[4];
  __shared__ float bval;
  int m = blockIdx.x;
  int tid = threadIdx.x, lane = tid & 63, wid = tid >> 6;
  float* rp = outp + (size_t)m * cV;
  float mx = -INFINITY;
  for (int n = tid; n < cV; n += 256) mx = fmaxf(mx, rp[n]);
#pragma unroll
  for (int off = 32; off >= 1; off >>= 1) mx = fmaxf(mx, __shfl_xor(mx, off));
  if (lane == 0) wred[wid] = mx;
  __syncthreads();
  if (tid == 0) bval = fmaxf(fmaxf(wred[0], wred[1]), fmaxf(wred[2], wred[3]));
  __syncthreads();
  mx = bval;
  float s = 0.f;
  for (int n = tid; n < cV; n += 256) s += expf(rp[n] - mx);
#pragma unroll
  for (int off = 32; off >= 1; off >>= 1) s += __shfl_xor(s, off);
  __syncthreads();
  if (lane == 0) wred[wid] = s;
  __syncthreads();
  if (tid == 0) bval = mx + logf(wred[0] + wred[1] + wred[2] + wred[3]);
  __syncthreads();
  float lz = bval;
  for (int n = tid; n < cV; n += 256) rp[n] = rp[n] - lz;
}

__global__ void k_scal(const float* __restrict__ scal, float* __restrict__ outp) {
  if (threadIdx.x == 0) {
    outp[LOGP_SZ + 2 * cB * cZ] = scal[0];
    outp[LOGP_SZ + 2 * cB * cZ + 1] = scal[1];
  }
}

extern "C" void kernel_launch(void* const* d_in, const int* in_sizes, int n_in,
                              void* d_out, int out_size, void* d_ws, size_t ws_size,
                              hipStream_t stream) {
  (void)in_sizes; (void)n_in; (void)out_size; (void)ws_size;
  const int* enc_input  = (const int*)d_in[0];
  const int* dec_input  = (const int*)d_in[1];
  const int* length     = (const int*)d_in[2];
  const float* eps      = (const float*)d_in[3];
  const float* enc_emb  = (const float*)d_in[4];
  const float* enc_Wih  = (const float*)d_in[5];
  const float* enc_Whh  = (const float*)d_in[6];
  const float* enc_bih  = (const float*)d_in[7];
  const float* enc_bhh  = (const float*)d_in[8];
  const float* latent_W = (const float*)d_in[9];
  const float* latent_b = (const float*)d_in[10];
  const float* dec_emb  = (const float*)d_in[11];
  const float* attn_W   = (const float*)d_in[12];
  const float* attn_b   = (const float*)d_in[13];
  const float* comb_W   = (const float*)d_in[14];
  const float* comb_b   = (const float*)d_in[15];
  const float* dec_Wih  = (const float*)d_in[16];
  const float* dec_Whh  = (const float*)d_in[17];
  const float* dec_bih  = (const float*)d_in[18];
  const float* dec_bhh  = (const float*)d_in[19];
  const float* pri_W    = (const float*)d_in[20];
  const float* pri_b    = (const float*)d_in[21];
  const float* inf_W    = (const float*)d_in[22];
  const float* inf_b    = (const float*)d_in[23];
  const float* aux_W    = (const float*)d_in[24];
  const float* aux_b    = (const float*)d_in[25];
  const float* out_W    = (const float*)d_in[26];
  const float* out_b    = (const float*)d_in[27];
  float* outp = (float*)d_out;

  // ---- scratch layout in the logp head (dead before k_logit) ----
  float* outF = outp;
  size_t off = 0;
  float* c_enc = outF + off; off += cB * cH;            // zeroed
  float* c_dec = outF + off; off += cB * cH;            // zeroed
  float* scal  = outF + off; off += 4;                  // zeroed
  u16* HencA = (u16*)(outF + off); off += cB * cH / 2;  // zeroed
  u16* HdecA = (u16*)(outF + off); off += cB * cH / 2;  // zeroed
  size_t zeroSpan = off;                                // 196,612 f32
  u16* HencB = (u16*)(outF + off); off += cB * cH / 2;
  u16* HdecB = (u16*)(outF + off); off += cB * cH / 2;
  u16* Ubuf  = (u16*)(outF + off); off += cB * cH / 2;
  u16* XU    = (u16*)(outF + off); off += (size_t)cB * 1792 / 2;
  float* mulv = outF + off; off += cB * 256;
  float* biasE = outF + off; off += 4 * cH;
  float* biasD = outF + off; off += 4 * cH;
  u16* encO = (u16*)(outF + off); off += (size_t)cB * cT * cH / 2;
  u16* Xenc = (u16*)(outF + off); off += (size_t)cT * cB * cE / 2;
  u16* Xdec = (u16*)(outF + off); off += (size_t)cTP1 * cB * cE / 2;
  u16* WpE  = (u16*)(outF + off); off += (size_t)4 * cH * (cE + cH) / 2;
  u16* WpD  = (u16*)(outF + off); off += (size_t)4 * cH * (2 * cH) / 2;
  u16* Wc   = (u16*)(outF + off); off += (size_t)cH * 1792 / 2;
  u16* wAttn = (u16*)(outF + off); off += (size_t)cT * 1536 / 2;
  u16* wPri  = (u16*)(outF + off); off += (size_t)256 * cH / 2;
  u16* wInf  = (u16*)(outF + off); off += (size_t)256 * 2 * cH / 2;
  u16* wAux  = (u16*)(outF + off); off += (size_t)cH * cZ / 2;
  // total ~12.9M f32 (~51 MB) << AMAT_OFF
  u16* Amat = (u16*)(outF + AMAT_OFF);  // logp tail
  u16* wsA = (u16*)d_ws;                // 256 KB proven

  // ---- prep (once per launch) ----
  k_prep_lstm<<<4 * cH, 256, 0, stream>>>(enc_Wih, enc_Whh, enc_bih, enc_bhh, cE, WpE, biasE);
  k_prep_lstm<<<4 * cH, 256, 0, stream>>>(dec_Wih, dec_Whh, dec_bih, dec_bhh, cH, WpD, biasD);
  k_cvt<<<1024, 256, 0, stream>>>(comb_W, Wc, cH * 1792);
  k_cvt<<<96, 256, 0, stream>>>(attn_W, wAttn, cT * 1536);
  k_cvt<<<256, 256, 0, stream>>>(pri_W, wPri, 256 * cH);
  k_cvt<<<512, 256, 0, stream>>>(inf_W, wInf, 256 * 2 * cH);
  k_cvt<<<128, 256, 0, stream>>>(aux_W, wAux, cH * cZ);
  k_gather<<<cT * cB, 256, 0, stream>>>(enc_input, enc_emb, Xenc, cT);
  k_gather<<<cTP1 * cB, 256, 0, stream>>>(dec_input, dec_emb, Xdec, cTP1);
  k_zero<<<(int)((zeroSpan + 255) / 256), 256, 0, stream>>>(c_enc, (int)zeroSpan);

  // ---- encoder: 64 fused MFMA steps ----
  for (int t = 0; t < cT; t++) {
    const u16* hin = (t & 1) ? HencB : HencA;
    u16* hout = (t & 1) ? HencA : HencB;
    k_cell<cE, cT><<<256, 64, 0, stream>>>(Xenc + (size_t)t * cB * cE, hin, WpE, biasE,
                                           c_enc, hout, encO, t);
  }
  // final h in HencA (t=63 writes A), c in c_enc
  k_latent<<<cB, 256, 0, stream>>>(HencA, c_enc, latent_W, latent_b, mulv, outp);
  k_z<<<(cB * cZ + 255) / 256, 256, 0, stream>>>(mulv, eps, XU);

  // ---- decoder: 65 steps x {mid, comb, cell} ----
  for (int t = 0; t < cTP1; t++) {
    const u16* hin = (t & 1) ? HdecB : HdecA;
    u16* hout = (t & 1) ? HdecA : HdecB;
    k_mid<<<cB, 256, 0, stream>>>(hin, Xdec, encO, enc_input, wAttn, attn_b,
                                  wPri, pri_b, wInf, inf_b, wAux, aux_b,
                                  length, XU, scal, t);
    k_comb<<<64, 64, 0, stream>>>(XU, Wc, comb_b, Ubuf);
    k_cell<cH, cTP1><<<256, 64, 0, stream>>>(Ubuf, hin, WpD, biasD,
                                             c_dec, hout, Amat, t);
  }

  // kld/aux scalars BEFORE k_logit (scal lives in logp scratch)
  k_scal<<<1, 64, 0, stream>>>(scal, outp);

  // ---- output projection + log-softmax ----
  k_cpyA<<<64, 256, 0, stream>>>(Amat, wsA);
  k_logit<<<32 * 500, 256, 0, stream>>>(Amat, 0, 0, 0, 4093, out_W, out_b, outp);
  k_logit<<<500, 256, 0, stream>>>(wsA, 4032, 4032, 4093, 4160, out_W, out_b, outp);
  k_lsm<<<cB * cTP1, 256, 0, stream>>>(outp);
}

// Round 8
// 5420.839 us; speedup vs baseline: 8.4567x; 2.1278x over previous
//
#include <hip/hip_runtime.h>
#include <hip/hip_bf16.h>
#include <cmath>

typedef unsigned short u16;
typedef __attribute__((ext_vector_type(8))) short short8;
typedef __attribute__((ext_vector_type(4))) float floatx4;

#define DEVI __device__ __forceinline__

constexpr int cV = 32000, cE = 512, cT = 64, cH = 1024, cZ = 128, cB = 64, cPAD = 31999, cTP1 = 65;
constexpr long long LOGP_SZ = 133120000LL;   // B*(T+1)*V f32 elems
constexpr long long AMAT_OFF = 130990080LL;  // LOGP_SZ - 4160*1024/2

DEVI float b2f(u16 u) { return __uint_as_float(((unsigned)u) << 16); }
DEVI u16 f2b(float f) {
  unsigned u = __float_as_uint(f);
  unsigned r = u + 0x7FFFu + ((u >> 16) & 1u);
  return (u16)(r >> 16);
}
DEVI unsigned pk2(float lo, float hi) {
  __hip_bfloat162 t = __float22bfloat162_rn(make_float2(lo, hi));
  return *reinterpret_cast<unsigned*>(&t);
}
DEVI float sigm(float x) { return 1.f / (1.f + expf(-x)); }

DEVI short8 ldfragW(const float* __restrict__ p) {  // 8 f32 -> bf16 frag
  float4 x = *(const float4*)p, y = *(const float4*)(p + 4);
  union { unsigned u[4]; short8 s; } r;
  r.u[0] = pk2(x.x, x.y); r.u[1] = pk2(x.z, x.w);
  r.u[2] = pk2(y.x, y.y); r.u[3] = pk2(y.z, y.w);
  return r.s;
}

template <typename T>
DEVI short8 ldfrag(const T* __restrict__ p) {
  if constexpr (sizeof(T) == 2) return *(const short8*)p;
  else return ldfragW((const float*)p);
}

template <int MAP>
DEVI int rmap(int r) {
  if constexpr (MAP == 1) return ((r & 3) << 10) | (r >> 2);  // n' -> g*1024+j
  else if constexpr (MAP == 2) return r & 63;                 // (t,b) row -> b
  else return r;
}

// f32 dot for k_latent
DEVI float dot_wf(const float* __restrict__ w, const float* __restrict__ s, int K) {
  float a0 = 0.f, a1 = 0.f, a2 = 0.f, a3 = 0.f;
#pragma unroll 4
  for (int k = 0; k < K; k += 8) {
    float4 p = *(const float4*)(w + k);
    float4 q = *(const float4*)(w + k + 4);
    a0 = fmaf(s[k + 0], p.x, a0); a1 = fmaf(s[k + 1], p.y, a1);
    a2 = fmaf(s[k + 2], p.z, a2); a3 = fmaf(s[k + 3], p.w, a3);
    a0 = fmaf(s[k + 4], q.x, a0); a1 = fmaf(s[k + 5], q.y, a1);
    a2 = fmaf(s[k + 6], q.z, a2); a3 = fmaf(s[k + 7], q.w, a3);
  }
  return (a0 + a1) + (a2 + a3);
}

__global__ __launch_bounds__(256) void k_zero(float* p, int n) {
  int i = blockIdx.x * 256 + threadIdx.x;
  if (i < n) p[i] = 0.f;
}

// ---------- generic MFMA GEMM: C[M,N] (+bias +D +C) = A[M,K] x B[N,K]^T ----------
// grid (N/16, M/64), 64 threads. AMAP/BMAP: row remap for A/B (and D follows AMAP).
template <typename AT, typename BT, typename CT, int AMAP, int BMAP, bool ADDC>
__global__ __launch_bounds__(64) void k_gemm(
    const AT* __restrict__ A, int lda, const BT* __restrict__ B, int ldb,
    const float* __restrict__ bias, const float* __restrict__ Dm, int ldd,
    CT* __restrict__ C, int ldc, int K) {
  int nblk = blockIdx.x, mblk = blockIdx.y;
  int lane = threadIdx.x;
  int lr = lane & 15, kg = lane >> 4;
  const BT* Bp = B + (size_t)rmap<BMAP>(nblk * 16 + lr) * ldb + kg * 8;
  const AT* Ap[4];
#pragma unroll
  for (int mf = 0; mf < 4; mf++)
    Ap[mf] = A + (size_t)rmap<AMAP>(mblk * 64 + mf * 16 + lr) * lda + kg * 8;
  floatx4 acc[4];
#pragma unroll
  for (int mf = 0; mf < 4; mf++) acc[mf] = (floatx4){0.f, 0.f, 0.f, 0.f};
#pragma unroll 4
  for (int ks = 0; ks < K / 32; ks++) {
    short8 bv = ldfrag(Bp + ks * 32);
#pragma unroll
    for (int mf = 0; mf < 4; mf++) {
      short8 av = ldfrag(Ap[mf] + ks * 32);
      acc[mf] = __builtin_amdgcn_mfma_f32_16x16x32_bf16(av, bv, acc[mf], 0, 0, 0);
    }
  }
  int n = nblk * 16 + lr;
  float bs = bias ? bias[n] : 0.f;
#pragma unroll
  for (int mf = 0; mf < 4; mf++) {
#pragma unroll
    for (int jj = 0; jj < 4; jj++) {
      int m = mblk * 64 + mf * 16 + kg * 4 + jj;
      size_t ci = (size_t)m * ldc + n;
      float v = acc[mf][jj] + bs;
      if (Dm) v += Dm[(size_t)rmap<AMAP>(m) * ldd + n];
      if constexpr (ADDC) {
        if constexpr (sizeof(CT) == 2) v += b2f(C[ci]);
        else v += C[ci];
      }
      if constexpr (sizeof(CT) == 2) C[ci] = f2b(v);
      else C[ci] = v;
    }
  }
}

// ---------- serial step: gates = G[t] + Wbig x h; LSTM cell; write h history ----------
__global__ __launch_bounds__(64) void k_cell2(
    const u16* __restrict__ G,   // [64][4096] bf16 (n'-permuted, biases folded)
    const u16* __restrict__ H, int strideH,
    const u16* __restrict__ Wb,  // [4096][1024] bf16 (rows n'-permuted)
    float* __restrict__ c, u16* __restrict__ out1, int s1,
    u16* __restrict__ out2, long long s2) {
  int nb = blockIdx.x;  // 0..255
  int lane = threadIdx.x;
  int lr = lane & 15, kg = lane >> 4;
  const u16* Bp = Wb + (size_t)(nb * 16 + lr) * cH + kg * 8;
  floatx4 acc[4];
#pragma unroll
  for (int mf = 0; mf < 4; mf++) acc[mf] = (floatx4){0.f, 0.f, 0.f, 0.f};
#pragma unroll 8
  for (int ks = 0; ks < 32; ks++) {
    short8 bv = *(const short8*)(Bp + ks * 32);
#pragma unroll
    for (int mf = 0; mf < 4; mf++) {
      short8 av = *(const short8*)(H + (size_t)(mf * 16 + lr) * strideH + ks * 32 + kg * 8);
      acc[mf] = __builtin_amdgcn_mfma_f32_16x16x32_bf16(av, bv, acc[mf], 0, 0, 0);
    }
  }
  __shared__ float lds[16][65];
#pragma unroll
  for (int mf = 0; mf < 4; mf++)
#pragma unroll
    for (int jj = 0; jj < 4; jj++)
      lds[lr][mf * 16 + kg * 4 + jj] = acc[mf][jj];
  __syncthreads();
#pragma unroll
  for (int a = 0; a < 4; a++) {
    int b = lane;
    int j = nb * 4 + a;
    ushort4 gv = *(const ushort4*)(G + (size_t)b * 4096 + nb * 16 + 4 * a);
    float gi = lds[4 * a + 0][b] + b2f(gv.x);
    float gf = lds[4 * a + 1][b] + b2f(gv.y);
    float gg = lds[4 * a + 2][b] + b2f(gv.z);
    float go = lds[4 * a + 3][b] + b2f(gv.w);
    int ci = b * cH + j;
    float cc = c[ci];
    cc = sigm(gf) * cc + sigm(gi) * tanhf(gg);
    float hh = sigm(go) * tanhf(cc);
    c[ci] = cc;
    u16 hb = f2b(hh);
    out1[(size_t)b * s1 + j] = hb;
    if (out2) out2[(size_t)b * s2 + j] = hb;
  }
}

// ---------- small prep kernels ----------
__global__ __launch_bounds__(256) void k_tr(const float* __restrict__ src, int ld,
                                            int R, float* __restrict__ dst) {
  __shared__ float tile[32][33];
  int c0 = blockIdx.x * 32, r0 = blockIdx.y * 32;
  int tx = threadIdx.x & 31, ty = threadIdx.x >> 5;
  for (int i = ty; i < 32; i += 8) tile[i][tx] = src[(size_t)(r0 + i) * ld + c0 + tx];
  __syncthreads();
  for (int i = ty; i < 32; i += 8) dst[(size_t)(c0 + i) * R + r0 + tx] = tile[tx][i];
}

__global__ __launch_bounds__(256) void k_gemv(const float* __restrict__ W, int ld,
                                              const float* __restrict__ x,
                                              const float* __restrict__ b,
                                              float* __restrict__ out, int K, int add) {
  int n = blockIdx.x * 256 + threadIdx.x;
  const float* w = W + (size_t)n * ld;
  float s = b ? b[n] : 0.f;
  for (int k = 0; k < K; k += 4) {
    float4 wv = *(const float4*)(w + k);
    float4 xv = *(const float4*)(x + k);
    s += wv.x * xv.x + wv.y * xv.y + wv.z * xv.z + wv.w * xv.w;
  }
  if (add) out[n] += s; else out[n] = s;
}

__global__ __launch_bounds__(256) void k_biasD(const float* __restrict__ bih,
                                               const float* __restrict__ bhh,
                                               const float* __restrict__ Wih,
                                               const float* __restrict__ u0,
                                               float* __restrict__ biasD) {
  int np = blockIdx.x * 256 + threadIdx.x;  // 4096
  int src = ((np & 3) << 10) | (np >> 2);
  const float* w = Wih + (size_t)src * cH;
  float s = bih[src] + bhh[src];
  for (int k = 0; k < cH; k += 4) {
    float4 wv = *(const float4*)(w + k);
    float4 xv = *(const float4*)(u0 + k);
    s += wv.x * xv.x + wv.y * xv.y + wv.z * xv.z + wv.w * xv.w;
  }
  biasD[np] = s;
}

__global__ __launch_bounds__(256) void k_biasE(const float* __restrict__ bih,
                                               const float* __restrict__ bhh,
                                               float* __restrict__ biasE) {
  int np = blockIdx.x * 256 + threadIdx.x;
  int src = ((np & 3) << 10) | (np >> 2);
  biasE[np] = bih[src] + bhh[src];
}

// permute+convert Whh: Wp[n'][k] = bf16(Whh[src(n')][k])
__global__ __launch_bounds__(256) void k_permW(const float* __restrict__ Whh,
                                               u16* __restrict__ Wp) {
  int np = blockIdx.x;
  int src = ((np & 3) << 10) | (np >> 2);
  const float* w = Whh + (size_t)src * cH;
  u16* d = Wp + (size_t)np * cH;
  int tid = threadIdx.x;
#pragma unroll
  for (int p = 0; p < 4; p++) d[tid + p * 256] = f2b(w[tid + p * 256]);
}

__global__ __launch_bounds__(256) void k_gather(const int* __restrict__ tok,
                                                const float* __restrict__ emb,
                                                u16* __restrict__ dst, int Tlen) {
  int r = blockIdx.x;  // t*64+b
  int t = r >> 6, b = r & 63;
  const float* src = emb + (size_t)tok[b * Tlen + t] * cE;
  u16* d = dst + (size_t)r * cE;
  int tid = threadIdx.x;
  for (int k = tid; k < cE; k += 256) d[k] = f2b(src[k]);
}

// ---------- latent / z ----------
__global__ __launch_bounds__(256) void k_latent(
    const u16* __restrict__ encO, const float* __restrict__ cT2,
    const float* __restrict__ W, const float* __restrict__ bias,
    float* __restrict__ mulv, float* __restrict__ outp) {
  __shared__ float s[2 * cH];
  int b = blockIdx.x;
  int n = threadIdx.x;
  for (int k = n; k < cH; k += 256) {
    s[k] = b2f(encO[((size_t)b * cT + 63) * cH + k]);
    s[cH + k] = cT2[b * cH + k];
  }
  __syncthreads();
  float acc = bias[n] + dot_wf(W + (size_t)n * (2 * cH), s, 2 * cH);
  mulv[b * 256 + n] = acc;
  if (n < cZ)
    outp[LOGP_SZ + (size_t)b * cZ + n] = acc;
  else
    outp[LOGP_SZ + (size_t)cB * cZ + (size_t)b * cZ + (n - cZ)] = acc;
}

__global__ __launch_bounds__(256) void k_z(const float* __restrict__ mulv,
                                           const float* __restrict__ eps,
                                           u16* __restrict__ zbuf) {
  int i = blockIdx.x * 256 + threadIdx.x;
  if (i >= cB * cZ) return;
  int b = i >> 7, zi = i & 127;
  float mu = mulv[b * 256 + zi], lv = mulv[b * 256 + cZ + zi];
  zbuf[i] = f2b(mu + expf(0.5f * lv) * eps[i]);
}

// ---------- post-hoc: softmax + ctx over all (t,b) ----------
__global__ __launch_bounds__(256) void k_sctx(
    const float* __restrict__ S, const int* __restrict__ enc_input,
    const u16* __restrict__ encO, u16* __restrict__ ctxH) {
  __shared__ float wat[cT];
  int tb = blockIdx.x;
  int t = tb >> 6, b = tb & 63;
  (void)t;
  int tid = threadIdx.x;
  if (tid < cT) {
    float sc = S[(size_t)tb * cT + tid];
    if (enc_input[b * cT + tid] == cPAD) sc = -INFINITY;
    float m = sc;
#pragma unroll
    for (int off = 32; off >= 1; off >>= 1) m = fmaxf(m, __shfl_xor(m, off));
    float p = expf(sc - m);
    float ssum = p;
#pragma unroll
    for (int off = 32; off >= 1; off >>= 1) ssum += __shfl_xor(ssum, off);
    wat[tid] = p / ssum;
  }
  __syncthreads();
#pragma unroll
  for (int p = 0; p < 4; p++) {
    int j = tid + p * 256;
    float s = 0.f;
    const u16* e = encO + ((size_t)b * cT) * cH + j;
#pragma unroll 8
    for (int t2 = 0; t2 < cT; t2++) s += wat[t2] * b2f(e[(size_t)t2 * cH]);
    ctxH[(size_t)tb * cH + j] = f2b(s);
  }
}

// ---------- post-hoc: kld + aux_c reductions ----------
__global__ __launch_bounds__(256) void k_scal_all(
    const float* __restrict__ priH, const float* __restrict__ infH,
    const u16* __restrict__ ctxH, const u16* __restrict__ auxH,
    const int* __restrict__ length, float* __restrict__ scal) {
  __shared__ float red[256];
  int tb = blockIdx.x;
  int t = tb >> 6, b = tb & 63;
  int tid = threadIdx.x;
  float r = 0.f;
  if (tid < cZ) {
    float pm = priH[(size_t)tb * 256 + tid], plv = priH[(size_t)tb * 256 + cZ + tid];
    float im = infH[(size_t)tb * 256 + tid], ilv = infH[(size_t)tb * 256 + cZ + tid];
    float d = im - pm;
    r = plv - ilv + expf(ilv - plv) + d * d * expf(-plv) - 1.f;
  }
  red[tid] = r;
  __syncthreads();
  for (int sft = 128; sft > 0; sft >>= 1) {
    if (tid < sft) red[tid] += red[tid + sft];
    __syncthreads();
  }
  if (tid == 0 && (length[b] + 1 > t)) atomicAdd(&scal[0], 0.5f * red[0]);
  __syncthreads();
  float r2 = 0.f;
#pragma unroll
  for (int p = 0; p < 4; p++) {
    int j = tid + p * 256;
    float d = b2f(ctxH[(size_t)tb * cH + j]) - b2f(auxH[(size_t)tb * cH + j]);
    r2 += d * d;
  }
  red[tid] = r2;
  __syncthreads();
  for (int sft = 128; sft > 0; sft >>= 1) {
    if (tid < sft) red[tid] += red[tid + sft];
    __syncthreads();
  }
  if (tid == 0) atomicAdd(&scal[1], red[0]);
}

__global__ void k_scal(const float* __restrict__ scal, float* __restrict__ outp) {
  if (threadIdx.x == 0) {
    outp[LOGP_SZ + 2 * cB * cZ] = scal[0];
    outp[LOGP_SZ + 2 * cB * cZ + 1] = scal[1];
  }
}

// ---------- output projection + log-softmax (proven round-7 kernels) ----------
__global__ __launch_bounds__(256) void k_cpyA(const u16* __restrict__ src,
                                              u16* __restrict__ dst) {
  int i = blockIdx.x * 256 + threadIdx.x;
  ((uint4*)dst)[i] = ((const uint4*)(src + (size_t)4032 * cH))[i];
}

__global__ __launch_bounds__(256) void k_logit(
    const u16* __restrict__ A, int aBase, int msBase, int mLo, int mHi,
    const float* __restrict__ Wv, const float* __restrict__ bias,
    float* __restrict__ outp) {
  int blk = blockIdx.x;
  int nb = blk % 500, mb = blk / 500;
  int wave = threadIdx.x >> 6, lane = threadIdx.x & 63;
  int wm = wave >> 1, wn = wave & 1;
  int ms = msBase + mb * 128 + wm * 64;
  int ns = nb * 64 + wn * 32;
  int lr = lane & 15, kg = lane >> 4;
  const short8* aP[4];
#pragma unroll
  for (int mi = 0; mi < 4; mi++) {
    int row = ms + mi * 16 + lr;
    if (row > cB * cTP1 - 1) row = cB * cTP1 - 1;
    aP[mi] = (const short8*)(A + (size_t)(row - aBase) * cH + kg * 8);
  }
  const float* bP0 = Wv + (size_t)(ns + lr) * cH + kg * 8;
  const float* bP1 = Wv + (size_t)(ns + 16 + lr) * cH + kg * 8;
  floatx4 acc[4][2];
#pragma unroll
  for (int mi = 0; mi < 4; mi++)
#pragma unroll
    for (int ni = 0; ni < 2; ni++) acc[mi][ni] = (floatx4){0.f, 0.f, 0.f, 0.f};
  for (int k0 = 0; k0 < cH; k0 += 32) {
    short8 bv0 = ldfragW(bP0 + k0);
    short8 bv1 = ldfragW(bP1 + k0);
#pragma unroll
    for (int mi = 0; mi < 4; mi++) {
      short8 av = aP[mi][k0 >> 3];
      acc[mi][0] = __builtin_amdgcn_mfma_f32_16x16x32_bf16(av, bv0, acc[mi][0], 0, 0, 0);
      acc[mi][1] = __builtin_amdgcn_mfma_f32_16x16x32_bf16(av, bv1, acc[mi][1], 0, 0, 0);
    }
  }
#pragma unroll
  for (int mi = 0; mi < 4; mi++) {
#pragma unroll
    for (int ni = 0; ni < 2; ni++) {
      int n = ns + ni * 16 + lr;
      float bb = bias[n];
#pragma unroll
      for (int jj = 0; jj < 4; jj++) {
        int m = ms + mi * 16 + kg * 4 + jj;
        if (m >= mLo && m < mHi)
          outp[(size_t)m * cV + n] = acc[mi][ni][jj] + bb;
      }
    }
  }
}

__global__ __launch_bounds__(256) void k_lsm(float* __restrict__ outp) {
  __shared__ float wred[4];
  __shared__ float bval;
  int m = blockIdx.x;
  int tid = threadIdx.x, lane = tid & 63, wid = tid >> 6;
  float* rp = outp + (size_t)m * cV;
  float mx = -INFINITY;
  for (int n = tid; n < cV; n += 256) mx = fmaxf(mx, rp[n]);
#pragma unroll
  for (int off = 32; off >= 1; off >>= 1) mx = fmaxf(mx, __shfl_xor(mx, off));
  if (lane == 0) wred[wid] = mx;
  __syncthreads();
  if (tid == 0) bval = fmaxf(fmaxf(wred[0], wred[1]), fmaxf(wred[2], wred[3]));
  __syncthreads();
  mx = bval;
  float s = 0.f;
  for (int n = tid; n < cV; n += 256) s += expf(rp[n] - mx);
#pragma unroll
  for (int off = 32; off >= 1; off >>= 1) s += __shfl_xor(s, off);
  __syncthreads();
  if (lane == 0) wred[wid] = s;
  __syncthreads();
  if (tid == 0) bval = mx + logf(wred[0] + wred[1] + wred[2] + wred[3]);
  __syncthreads();
  float lz = bval;
  for (int n = tid; n < cV; n += 256) rp[n] = rp[n] - lz;
}

extern "C" void kernel_launch(void* const* d_in, const int* in_sizes, int n_in,
                              void* d_out, int out_size, void* d_ws, size_t ws_size,
                              hipStream_t stream) {
  (void)in_sizes; (void)n_in; (void)out_size; (void)ws_size;
  const int* enc_input  = (const int*)d_in[0];
  const int* dec_input  = (const int*)d_in[1];
  const int* length     = (const int*)d_in[2];
  const float* eps      = (const float*)d_in[3];
  const float* enc_emb  = (const float*)d_in[4];
  const float* enc_Wih  = (const float*)d_in[5];
  const float* enc_Whh  = (const float*)d_in[6];
  const float* enc_bih  = (const float*)d_in[7];
  const float* enc_bhh  = (const float*)d_in[8];
  const float* latent_W = (const float*)d_in[9];
  const float* latent_b = (const float*)d_in[10];
  const float* dec_emb  = (const float*)d_in[11];
  const float* attn_W   = (const float*)d_in[12];
  const float* attn_b   = (const float*)d_in[13];
  const float* comb_W   = (const float*)d_in[14];
  const float* comb_b   = (const float*)d_in[15];
  const float* dec_Wih  = (const float*)d_in[16];
  const float* dec_Whh  = (const float*)d_in[17];
  const float* dec_bih  = (const float*)d_in[18];
  const float* dec_bhh  = (const float*)d_in[19];
  const float* pri_W    = (const float*)d_in[20];
  const float* pri_b    = (const float*)d_in[21];
  const float* inf_W    = (const float*)d_in[22];
  const float* inf_b    = (const float*)d_in[23];
  const float* aux_W    = (const float*)d_in[24];
  const float* aux_b    = (const float*)d_in[25];
  const float* out_W    = (const float*)d_in[26];
  const float* out_b    = (const float*)d_in[27];
  float* outp = (float*)d_out;
  float* outF = outp;

  // ---- scratch layout in logp head (all dead before k_logit) ----
  size_t off = 0;
  float* c_enc = outF + off; off += 65536;
  float* c_dec = outF + off; off += 65536;
  float* scal  = outF + off; off += 4;
  off += 60;  // pad
  u16* HencZ = (u16*)(outF + off); off += 32768;
  u16* Hh    = (u16*)(outF + off); off += 66 * 32768;   // [66][64][1024]
  size_t zeroSpan = 196672;                              // c_enc .. Hh[0] incl.
  u16* encO  = (u16*)(outF + off); off += 2097152;       // [64b][64t][1024]
  u16* Xenc  = (u16*)(outF + off); off += 1048576;       // [64t][64b][512]
  u16* Xdec  = (u16*)(outF + off); off += 1064960;       // [65t][64b][512]
  u16* zbuf  = (u16*)(outF + off); off += 4096;          // [64][128]
  float* mulv  = outF + off; off += 16384;
  float* biasE = outF + off; off += 4096;
  float* biasD = outF + off; off += 4096;
  float* tmp1  = outF + off; off += 1024;
  float* u0    = outF + off; off += 1024;
  float* WcxT  = outF + off; off += 524288;   // [512][1024]
  float* WczT  = outF + off; off += 131072;   // [128][1024]
  float* wPmT  = outF + off; off += 131072;   // [1024][128]
  float* auxWT = outF + off; off += 131072;   // [128][1024]
  float* M1    = outF + off; off += 131072;   // [1024][128]
  float* WfT   = outF + off; off += 1048576;  // [1024][1024]
  u16* WhhEp = (u16*)(outF + off); off += 2097152;  // [4096][1024]
  u16* Wbig  = (u16*)(outF + off); off += 2097152;  // [4096][1024]
  u16* C1    = (u16*)(outF + off); off += 1048576;  // [4096][512]
  u16* C2    = (u16*)(outF + off); off += 262144;   // [4096][128]
  u16* Genc  = (u16*)(outF + off); off += 8388608;  // [64][64][4096]
  u16* Gdec  = (u16*)(outF + off); off += 8519680;  // [65][64][4096]
  float* priH = outF + off; off += 1064960;  // [4160][256]
  float* infH = outF + off; off += 1064960;  // [4160][256]
  float* S    = outF + off; off += 266240;   // [4160][64]
  u16* ctxH  = (u16*)(outF + off); off += 2129920;  // [4160][1024]
  u16* auxH  = (u16*)(outF + off); off += 2129920;  // [4160][1024]
  u16* Amat = (u16*)(outF + AMAT_OFF);
  u16* wsA = (u16*)d_ws;

  // ---- prep: transposes, biases, permutes, gathers ----
  k_tr<<<dim3(16, 32), 256, 0, stream>>>(comb_W, 1792, 1024, WcxT);          // cols 0..512
  k_tr<<<dim3(4, 32), 256, 0, stream>>>(comb_W + 1664, 1792, 1024, WczT);    // cols 1664..1792
  k_tr<<<dim3(32, 4), 256, 0, stream>>>(pri_W, 1024, 128, wPmT);             // rows 0..128
  k_tr<<<dim3(4, 32), 256, 0, stream>>>(aux_W, 128, 1024, auxWT);
  k_gemv<<<4, 256, 0, stream>>>(aux_W, 128, pri_b, aux_b, tmp1, 128, 0);     // tmp1 = auxW*pm_b + aux_b
  k_gemv<<<4, 256, 0, stream>>>(comb_W + 512, 1792, tmp1, comb_b, u0, 1024, 0);
  k_gemv<<<4, 256, 0, stream>>>(comb_W + 1536, 1792, pri_b, nullptr, u0, 128, 1);
  k_biasE<<<16, 256, 0, stream>>>(enc_bih, enc_bhh, biasE);
  k_biasD<<<16, 256, 0, stream>>>(dec_bih, dec_bhh, dec_Wih, u0, biasD);
  k_permW<<<4096, 256, 0, stream>>>(enc_Whh, WhhEp);
  k_gather<<<cT * cB, 256, 0, stream>>>(enc_input, enc_emb, Xenc, cT);
  k_gather<<<cTP1 * cB, 256, 0, stream>>>(dec_input, dec_emb, Xdec, cTP1);
  k_zero<<<(int)((zeroSpan + 255) / 256), 256, 0, stream>>>(c_enc, (int)zeroSpan);

  // ---- weight composition (f32 accum GEMMs) ----
  // M1[u,z] = Wca x auxW + Wcp
  k_gemm<float, float, float, 0, 0, false><<<dim3(8, 16), 64, 0, stream>>>(
      comb_W + 512, 1792, auxWT, 1024, nullptr, comb_W + 1536, 1792, M1, 128, 1024);
  // WfT[h,u] = wPmT x M1^T
  k_gemm<float, float, float, 0, 0, false><<<dim3(64, 16), 64, 0, stream>>>(
      wPmT, 128, M1, 128, nullptr, nullptr, 0, WfT, 1024, 128);
  // Wbig[n',h] = Wih_d(perm) x WfT^T + Whh_d(perm)
  k_gemm<float, float, u16, 1, 0, false><<<dim3(64, 64), 64, 0, stream>>>(
      dec_Wih, 1024, WfT, 1024, nullptr, dec_Whh, 1024, Wbig, 1024, 1024);
  // C1[n',e] = Wih_d(perm) x WcxT^T ; C2[n',z] = Wih_d(perm) x WczT^T
  k_gemm<float, float, u16, 1, 0, false><<<dim3(32, 64), 64, 0, stream>>>(
      dec_Wih, 1024, WcxT, 1024, nullptr, nullptr, 0, C1, 512, 1024);
  k_gemm<float, float, u16, 1, 0, false><<<dim3(8, 64), 64, 0, stream>>>(
      dec_Wih, 1024, WczT, 1024, nullptr, nullptr, 0, C2, 128, 1024);
  // Genc = Xenc x enc_Wih(perm)^T + biasE
  k_gemm<u16, float, u16, 0, 1, false><<<dim3(256, 64), 64, 0, stream>>>(
      Xenc, 512, enc_Wih, 512, biasE, nullptr, 0, Genc, 4096, 512);

  // ---- encoder loop (64 x 1 kernel) ----
  for (int t = 0; t < cT; t++) {
    const u16* Hcur = t ? (encO + (size_t)(t - 1) * cH) : HencZ;
    int sH = t ? (cT * cH) : cH;
    k_cell2<<<256, 64, 0, stream>>>(Genc + (size_t)t * cB * 4096, Hcur, sH, WhhEp,
                                    c_enc, encO + (size_t)t * cH, cT * cH, nullptr, 0);
  }
  k_latent<<<cB, 256, 0, stream>>>(encO, c_enc, latent_W, latent_b, mulv, outp);
  k_z<<<(cB * cZ + 255) / 256, 256, 0, stream>>>(mulv, eps, zbuf);

  // ---- Gdec = Xdec x C1^T + biasD ; += zbuf x C2^T ----
  k_gemm<u16, u16, u16, 0, 0, false><<<dim3(256, 65), 64, 0, stream>>>(
      Xdec, 512, C1, 512, biasD, nullptr, 0, Gdec, 4096, 512);
  k_gemm<u16, u16, u16, 2, 0, true><<<dim3(256, 65), 64, 0, stream>>>(
      zbuf, 128, C2, 128, nullptr, nullptr, 0, Gdec, 4096, 128);

  // ---- decoder loop (65 x 1 kernel) ----
  for (int t = 0; t < cTP1; t++) {
    k_cell2<<<256, 64, 0, stream>>>(Gdec + (size_t)t * cB * 4096,
                                    Hh + (size_t)t * cB * cH, cH, Wbig, c_dec,
                                    Hh + (size_t)(t + 1) * cB * cH, cH,
                                    Amat + (size_t)t * cH, (long long)cTP1 * cH);
  }

  // ---- post-hoc batched non-critical math ----
  k_gemm<u16, float, float, 0, 0, false><<<dim3(16, 65), 64, 0, stream>>>(
      Hh, 1024, pri_W, 1024, pri_b, nullptr, 0, priH, 256, 1024);
  k_gemm<u16, float, float, 0, 0, false><<<dim3(4, 65), 64, 0, stream>>>(
      Xdec, 512, attn_W, 1536, attn_b, nullptr, 0, S, 64, 512);
  k_gemm<u16, float, float, 0, 0, true><<<dim3(4, 65), 64, 0, stream>>>(
      Hh, 1024, attn_W + 512, 1536, nullptr, nullptr, 0, S, 64, 1024);
  k_sctx<<<cTP1 * cB, 256, 0, stream>>>(S, enc_input, encO, ctxH);
  k_gemm<u16, float, float, 0, 0, false><<<dim3(16, 65), 64, 0, stream>>>(
      Hh, 1024, inf_W, 2048, inf_b, nullptr, 0, infH, 256, 1024);
  k_gemm<u16, float, float, 0, 0, true><<<dim3(16, 65), 64, 0, stream>>>(
      ctxH, 1024, inf_W + 1024, 2048, nullptr, nullptr, 0, infH, 256, 1024);
  k_gemm<float, float, u16, 0, 0, false><<<dim3(64, 65), 64, 0, stream>>>(
      priH, 256, aux_W, 128, aux_b, nullptr, 0, auxH, 1024, 128);
  k_scal_all<<<cTP1 * cB, 256, 0, stream>>>(priH, infH, ctxH, auxH, length, scal);
  k_scal<<<1, 64, 0, stream>>>(scal, outp);

  // ---- output projection + log-softmax ----
  k_cpyA<<<64, 256, 0, stream>>>(Amat, wsA);
  k_logit<<<32 * 500, 256, 0, stream>>>(Amat, 0, 0, 0, 4093, out_W, out_b, outp);
  k_logit<<<500, 256, 0, stream>>>(wsA, 4032, 4032, 4093, 4160, out_W, out_b, outp);
  k_lsm<<<cB * cTP1, 256, 0, stream>>>(outp);
}

// Round 9
// 4820.041 us; speedup vs baseline: 9.5108x; 1.1246x over previous
//
#include <hip/hip_runtime.h>
#include <hip/hip_bf16.h>
#include <cmath>

typedef unsigned short u16;
typedef __attribute__((ext_vector_type(8))) short short8;
typedef __attribute__((ext_vector_type(4))) float floatx4;

#define DEVI __device__ __forceinline__

constexpr int cV = 32000, cE = 512, cT = 64, cH = 1024, cZ = 128, cB = 64, cPAD = 31999, cTP1 = 65;
constexpr long long LOGP_SZ = 133120000LL;   // B*(T+1)*V f32 elems
constexpr long long AMAT_OFF = 130990080LL;  // LOGP_SZ - 4160*1024/2
constexpr long long WBOUT_OFF = 38400000LL;  // row 1200 * 32000 ; 32.768M bf16 -> rows [1200,1712)
constexpr int SKIP_LO = 1200, SKIP_HI = 1712;

DEVI float b2f(u16 u) { return __uint_as_float(((unsigned)u) << 16); }
DEVI u16 f2b(float f) {
  unsigned u = __float_as_uint(f);
  unsigned r = u + 0x7FFFu + ((u >> 16) & 1u);
  return (u16)(r >> 16);
}
DEVI unsigned pk2(float lo, float hi) {
  __hip_bfloat162 t = __float22bfloat162_rn(make_float2(lo, hi));
  return *reinterpret_cast<unsigned*>(&t);
}
DEVI float sigm(float x) { return 1.f / (1.f + expf(-x)); }

DEVI short8 ldfragW(const float* __restrict__ p) {  // 8 f32 -> bf16 frag
  float4 x = *(const float4*)p, y = *(const float4*)(p + 4);
  union { unsigned u[4]; short8 s; } r;
  r.u[0] = pk2(x.x, x.y); r.u[1] = pk2(x.z, x.w);
  r.u[2] = pk2(y.x, y.y); r.u[3] = pk2(y.z, y.w);
  return r.s;
}

template <typename T>
DEVI short8 ldfrag(const T* __restrict__ p) {
  if constexpr (sizeof(T) == 2) return *(const short8*)(p);
  else return ldfragW((const float*)p);
}

template <int MAP>
DEVI int rmap(int r) {
  if constexpr (MAP == 1) return ((r & 3) << 10) | (r >> 2);  // n' -> g*1024+j
  else if constexpr (MAP == 2) return r & 63;                 // (t,b) row -> b
  else return r;
}

DEVI float dot_wf(const float* __restrict__ w, const float* __restrict__ s, int K) {
  float a0 = 0.f, a1 = 0.f, a2 = 0.f, a3 = 0.f;
#pragma unroll 4
  for (int k = 0; k < K; k += 8) {
    float4 p = *(const float4*)(w + k);
    float4 q = *(const float4*)(w + k + 4);
    a0 = fmaf(s[k + 0], p.x, a0); a1 = fmaf(s[k + 1], p.y, a1);
    a2 = fmaf(s[k + 2], p.z, a2); a3 = fmaf(s[k + 3], p.w, a3);
    a0 = fmaf(s[k + 4], q.x, a0); a1 = fmaf(s[k + 5], q.y, a1);
    a2 = fmaf(s[k + 6], q.z, a2); a3 = fmaf(s[k + 7], q.w, a3);
  }
  return (a0 + a1) + (a2 + a3);
}

__global__ __launch_bounds__(256) void k_zero(float* p, int n) {
  int i = blockIdx.x * 256 + threadIdx.x;
  if (i < n) p[i] = 0.f;
}

// ---------- generic MFMA GEMM: C[M,N] (+bias +D +C) = A[M,K] x B[N,K]^T ----------
template <typename AT, typename BT, typename CT, int AMAP, int BMAP, bool ADDC>
__global__ __launch_bounds__(64) void k_gemm(
    const AT* __restrict__ A, int lda, const BT* __restrict__ B, int ldb,
    const float* __restrict__ bias, const float* __restrict__ Dm, int ldd,
    CT* __restrict__ C, int ldc, int K) {
  int nblk = blockIdx.x, mblk = blockIdx.y;
  int lane = threadIdx.x;
  int lr = lane & 15, kg = lane >> 4;
  const BT* Bp = B + (size_t)rmap<BMAP>(nblk * 16 + lr) * ldb + kg * 8;
  const AT* Ap[4];
#pragma unroll
  for (int mf = 0; mf < 4; mf++)
    Ap[mf] = A + (size_t)rmap<AMAP>(mblk * 64 + mf * 16 + lr) * lda + kg * 8;
  floatx4 acc[4];
#pragma unroll
  for (int mf = 0; mf < 4; mf++) acc[mf] = (floatx4){0.f, 0.f, 0.f, 0.f};
#pragma unroll 4
  for (int ks = 0; ks < K / 32; ks++) {
    short8 bv = ldfrag(Bp + ks * 32);
#pragma unroll
    for (int mf = 0; mf < 4; mf++) {
      short8 av = ldfrag(Ap[mf] + ks * 32);
      acc[mf] = __builtin_amdgcn_mfma_f32_16x16x32_bf16(av, bv, acc[mf], 0, 0, 0);
    }
  }
  int n = nblk * 16 + lr;
  float bs = bias ? bias[n] : 0.f;
#pragma unroll
  for (int mf = 0; mf < 4; mf++) {
#pragma unroll
    for (int jj = 0; jj < 4; jj++) {
      int m = mblk * 64 + mf * 16 + kg * 4 + jj;
      size_t ci = (size_t)m * ldc + n;
      float v = acc[mf][jj] + bs;
      if (Dm) v += Dm[(size_t)rmap<AMAP>(m) * ldd + n];
      if constexpr (ADDC) {
        if constexpr (sizeof(CT) == 2) v += b2f(C[ci]);
        else v += C[ci];
      }
      if constexpr (sizeof(CT) == 2) C[ci] = f2b(v);
      else C[ci] = v;
    }
  }
}

// ---------- serial step: gates = G[t] + Wbig x h; LSTM cell ----------
__global__ __launch_bounds__(64) void k_cell2(
    const u16* __restrict__ G, const u16* __restrict__ H, int strideH,
    const u16* __restrict__ Wb, float* __restrict__ c,
    u16* __restrict__ out1, int s1, u16* __restrict__ out2, long long s2) {
  int nb = blockIdx.x;
  int lane = threadIdx.x;
  int lr = lane & 15, kg = lane >> 4;
  const u16* Bp = Wb + (size_t)(nb * 16 + lr) * cH + kg * 8;
  floatx4 acc[4];
#pragma unroll
  for (int mf = 0; mf < 4; mf++) acc[mf] = (floatx4){0.f, 0.f, 0.f, 0.f};
#pragma unroll 8
  for (int ks = 0; ks < 32; ks++) {
    short8 bv = *(const short8*)(Bp + ks * 32);
#pragma unroll
    for (int mf = 0; mf < 4; mf++) {
      short8 av = *(const short8*)(H + (size_t)(mf * 16 + lr) * strideH + ks * 32 + kg * 8);
      acc[mf] = __builtin_amdgcn_mfma_f32_16x16x32_bf16(av, bv, acc[mf], 0, 0, 0);
    }
  }
  __shared__ float lds[16][65];
#pragma unroll
  for (int mf = 0; mf < 4; mf++)
#pragma unroll
    for (int jj = 0; jj < 4; jj++)
      lds[lr][mf * 16 + kg * 4 + jj] = acc[mf][jj];
  __syncthreads();
#pragma unroll
  for (int a = 0; a < 4; a++) {
    int b = lane;
    int j = nb * 4 + a;
    ushort4 gv = *(const ushort4*)(G + (size_t)b * 4096 + nb * 16 + 4 * a);
    float gi = lds[4 * a + 0][b] + b2f(gv.x);
    float gf = lds[4 * a + 1][b] + b2f(gv.y);
    float gg = lds[4 * a + 2][b] + b2f(gv.z);
    float go = lds[4 * a + 3][b] + b2f(gv.w);
    int ci = b * cH + j;
    float cc = c[ci];
    cc = sigm(gf) * cc + sigm(gi) * tanhf(gg);
    float hh = sigm(go) * tanhf(cc);
    c[ci] = cc;
    u16 hb = f2b(hh);
    out1[(size_t)b * s1 + j] = hb;
    if (out2) out2[(size_t)b * s2 + j] = hb;
  }
}

// ---------- small prep kernels ----------
__global__ __launch_bounds__(256) void k_tr(const float* __restrict__ src, int ld,
                                            int R, float* __restrict__ dst) {
  __shared__ float tile[32][33];
  int c0 = blockIdx.x * 32, r0 = blockIdx.y * 32;
  int tx = threadIdx.x & 31, ty = threadIdx.x >> 5;
  for (int i = ty; i < 32; i += 8) tile[i][tx] = src[(size_t)(r0 + i) * ld + c0 + tx];
  __syncthreads();
  for (int i = ty; i < 32; i += 8) dst[(size_t)(c0 + i) * R + r0 + tx] = tile[tx][i];
}

__global__ __launch_bounds__(256) void k_gemv(const float* __restrict__ W, int ld,
                                              const float* __restrict__ x,
                                              const float* __restrict__ b,
                                              float* __restrict__ out, int K, int add) {
  int n = blockIdx.x * 256 + threadIdx.x;
  const float* w = W + (size_t)n * ld;
  float s = b ? b[n] : 0.f;
  for (int k = 0; k < K; k += 4) {
    float4 wv = *(const float4*)(w + k);
    float4 xv = *(const float4*)(x + k);
    s += wv.x * xv.x + wv.y * xv.y + wv.z * xv.z + wv.w * xv.w;
  }
  if (add) out[n] += s; else out[n] = s;
}

__global__ __launch_bounds__(256) void k_biasD(const float* __restrict__ bih,
                                               const float* __restrict__ bhh,
                                               const float* __restrict__ Wih,
                                               const float* __restrict__ u0,
                                               float* __restrict__ biasD) {
  int np = blockIdx.x * 256 + threadIdx.x;
  int src = ((np & 3) << 10) | (np >> 2);
  const float* w = Wih + (size_t)src * cH;
  float s = bih[src] + bhh[src];
  for (int k = 0; k < cH; k += 4) {
    float4 wv = *(const float4*)(w + k);
    float4 xv = *(const float4*)(u0 + k);
    s += wv.x * xv.x + wv.y * xv.y + wv.z * xv.z + wv.w * xv.w;
  }
  biasD[np] = s;
}

__global__ __launch_bounds__(256) void k_biasE(const float* __restrict__ bih,
                                               const float* __restrict__ bhh,
                                               float* __restrict__ biasE) {
  int np = blockIdx.x * 256 + threadIdx.x;
  int src = ((np & 3) << 10) | (np >> 2);
  biasE[np] = bih[src] + bhh[src];
}

__global__ __launch_bounds__(256) void k_permW(const float* __restrict__ Whh,
                                               u16* __restrict__ Wp) {
  int np = blockIdx.x;
  int src = ((np & 3) << 10) | (np >> 2);
  const float* w = Whh + (size_t)src * cH;
  u16* d = Wp + (size_t)np * cH;
  int tid = threadIdx.x;
#pragma unroll
  for (int p = 0; p < 4; p++) d[tid + p * 256] = f2b(w[tid + p * 256]);
}

__global__ __launch_bounds__(256) void k_cvt(const float* __restrict__ in,
                                             u16* __restrict__ outp, int n) {
  int stride = gridDim.x * 256 * 4;
  for (int i = (blockIdx.x * 256 + threadIdx.x) * 4; i < n; i += stride) {
    float4 v = *(const float4*)(in + i);
    ushort4 r;
    r.x = f2b(v.x); r.y = f2b(v.y); r.z = f2b(v.z); r.w = f2b(v.w);
    *(ushort4*)(outp + i) = r;
  }
}

__global__ __launch_bounds__(256) void k_gather(const int* __restrict__ tok,
                                                const float* __restrict__ emb,
                                                u16* __restrict__ dst, int Tlen) {
  int r = blockIdx.x;
  int t = r >> 6, b = r & 63;
  const float* src = emb + (size_t)tok[b * Tlen + t] * cE;
  u16* d = dst + (size_t)r * cE;
  int tid = threadIdx.x;
  for (int k = tid; k < cE; k += 256) d[k] = f2b(src[k]);
}

// ---------- latent / z ----------
__global__ __launch_bounds__(256) void k_latent(
    const u16* __restrict__ encO, const float* __restrict__ cT2,
    const float* __restrict__ W, const float* __restrict__ bias,
    float* __restrict__ mulv, float* __restrict__ outp) {
  __shared__ float s[2 * cH];
  int b = blockIdx.x;
  int n = threadIdx.x;
  for (int k = n; k < cH; k += 256) {
    s[k] = b2f(encO[((size_t)b * cT + 63) * cH + k]);
    s[cH + k] = cT2[b * cH + k];
  }
  __syncthreads();
  float acc = bias[n] + dot_wf(W + (size_t)n * (2 * cH), s, 2 * cH);
  mulv[b * 256 + n] = acc;
  if (n < cZ)
    outp[LOGP_SZ + (size_t)b * cZ + n] = acc;
  else
    outp[LOGP_SZ + (size_t)cB * cZ + (size_t)b * cZ + (n - cZ)] = acc;
}

__global__ __launch_bounds__(256) void k_z(const float* __restrict__ mulv,
                                           const float* __restrict__ eps,
                                           u16* __restrict__ zbuf) {
  int i = blockIdx.x * 256 + threadIdx.x;
  if (i >= cB * cZ) return;
  int b = i >> 7, zi = i & 127;
  float mu = mulv[b * 256 + zi], lv = mulv[b * 256 + cZ + zi];
  zbuf[i] = f2b(mu + expf(0.5f * lv) * eps[i]);
}

// ---------- post-hoc: softmax + ctx ----------
__global__ __launch_bounds__(256) void k_sctx(
    const float* __restrict__ S, const int* __restrict__ enc_input,
    const u16* __restrict__ encO, u16* __restrict__ ctxH) {
  __shared__ float wat[cT];
  int tb = blockIdx.x;
  int b = tb & 63;
  int tid = threadIdx.x;
  if (tid < cT) {
    float sc = S[(size_t)tb * cT + tid];
    if (enc_input[b * cT + tid] == cPAD) sc = -INFINITY;
    float m = sc;
#pragma unroll
    for (int off = 32; off >= 1; off >>= 1) m = fmaxf(m, __shfl_xor(m, off));
    float p = expf(sc - m);
    float ssum = p;
#pragma unroll
    for (int off = 32; off >= 1; off >>= 1) ssum += __shfl_xor(ssum, off);
    wat[tid] = p / ssum;
  }
  __syncthreads();
#pragma unroll
  for (int p = 0; p < 4; p++) {
    int j = tid + p * 256;
    float s = 0.f;
    const u16* e = encO + ((size_t)b * cT) * cH + j;
#pragma unroll 8
    for (int t2 = 0; t2 < cT; t2++) s += wat[t2] * b2f(e[(size_t)t2 * cH]);
    ctxH[(size_t)tb * cH + j] = f2b(s);
  }
}

// ---------- post-hoc: kld + aux_c reductions ----------
__global__ __launch_bounds__(256) void k_scal_all(
    const float* __restrict__ priH, const float* __restrict__ infH,
    const u16* __restrict__ ctxH, const u16* __restrict__ auxH,
    const int* __restrict__ length, float* __restrict__ scal) {
  __shared__ float red[256];
  int tb = blockIdx.x;
  int t = tb >> 6, b = tb & 63;
  int tid = threadIdx.x;
  float r = 0.f;
  if (tid < cZ) {
    float pm = priH[(size_t)tb * 256 + tid], plv = priH[(size_t)tb * 256 + cZ + tid];
    float im = infH[(size_t)tb * 256 + tid], ilv = infH[(size_t)tb * 256 + cZ + tid];
    float d = im - pm;
    r = plv - ilv + expf(ilv - plv) + d * d * expf(-plv) - 1.f;
  }
  red[tid] = r;
  __syncthreads();
  for (int sft = 128; sft > 0; sft >>= 1) {
    if (tid < sft) red[tid] += red[tid + sft];
    __syncthreads();
  }
  if (tid == 0 && (length[b] + 1 > t)) atomicAdd(&scal[0], 0.5f * red[0]);
  __syncthreads();
  float r2 = 0.f;
#pragma unroll
  for (int p = 0; p < 4; p++) {
    int j = tid + p * 256;
    float d = b2f(ctxH[(size_t)tb * cH + j]) - b2f(auxH[(size_t)tb * cH + j]);
    r2 += d * d;
  }
  red[tid] = r2;
  __syncthreads();
  for (int sft = 128; sft > 0; sft >>= 1) {
    if (tid < sft) red[tid] += red[tid + sft];
    __syncthreads();
  }
  if (tid == 0) atomicAdd(&scal[1], red[0]);
}

__global__ void k_scal(const float* __restrict__ scal, float* __restrict__ outp) {
  if (threadIdx.x == 0) {
    outp[LOGP_SZ + 2 * cB * cZ] = scal[0];
    outp[LOGP_SZ + 2 * cB * cZ + 1] = scal[1];
  }
}

__global__ __launch_bounds__(256) void k_cpyA(const u16* __restrict__ src,
                                              u16* __restrict__ dst) {
  int i = blockIdx.x * 256 + threadIdx.x;
  ((uint4*)dst)[i] = ((const uint4*)(src + (size_t)4032 * cH))[i];
}

// ---- output projection v2: W panel staged in LDS (128 KB, swizzled), loop all M ----
// grid 500 (N/64), 512 threads (8 waves: 4 wm x 2 wn), 256 rows per m-iter.
template <typename WT>
__global__ __launch_bounds__(512) void k_logit2(
    const u16* __restrict__ A, int aBase,
    const WT* __restrict__ Wv, const float* __restrict__ bias,
    float* __restrict__ outp,
    int mStart, int mEnd, int skipLo, int skipHi, int storeLo) {
  extern __shared__ char smem[];  // 131072 B: 64 cols x 1024 bf16, swizzled
  int nb = blockIdx.x;
  int tid = threadIdx.x;
  for (int q = tid; q < 8192; q += 512) {   // 16B chunks
    int c = q >> 7, k8 = q & 127;
    short8 frag;
    if constexpr (sizeof(WT) == 2)
      frag = *(const short8*)(Wv + (size_t)(nb * 64 + c) * cH + k8 * 8);
    else
      frag = ldfragW((const float*)Wv + (size_t)(nb * 64 + c) * cH + k8 * 8);
    *(short8*)(smem + ((c * 2048 + k8 * 16) ^ ((c & 7) << 4))) = frag;
  }
  __syncthreads();
  int wave = tid >> 6, lane = tid & 63;
  int wm = wave >> 1, wn = wave & 1;
  int lr = lane & 15, kg = lane >> 4;
  int ns = nb * 64 + wn * 32;
  int c0 = wn * 32 + lr, c1 = wn * 32 + 16 + lr;
  for (int m0 = mStart; m0 < mEnd; m0 += 256) {
    int ms = m0 + wm * 64;
    const short8* aP[4];
#pragma unroll
    for (int mf = 0; mf < 4; mf++) {
      int row = ms + mf * 16 + lr;
      if (row > mEnd - 1) row = mEnd - 1;
      aP[mf] = (const short8*)(A + (size_t)(row - aBase) * cH + kg * 8);
    }
    floatx4 acc[4][2];
#pragma unroll
    for (int mf = 0; mf < 4; mf++)
#pragma unroll
      for (int ni = 0; ni < 2; ni++) acc[mf][ni] = (floatx4){0.f, 0.f, 0.f, 0.f};
#pragma unroll 4
    for (int ks = 0; ks < 32; ks++) {
      short8 bv0 = *(const short8*)(smem + ((c0 * 2048 + ks * 64 + kg * 16) ^ ((c0 & 7) << 4)));
      short8 bv1 = *(const short8*)(smem + ((c1 * 2048 + ks * 64 + kg * 16) ^ ((c1 & 7) << 4)));
#pragma unroll
      for (int mf = 0; mf < 4; mf++) {
        short8 av = aP[mf][ks * 4];
        acc[mf][0] = __builtin_amdgcn_mfma_f32_16x16x32_bf16(av, bv0, acc[mf][0], 0, 0, 0);
        acc[mf][1] = __builtin_amdgcn_mfma_f32_16x16x32_bf16(av, bv1, acc[mf][1], 0, 0, 0);
      }
    }
#pragma unroll
    for (int mf = 0; mf < 4; mf++) {
#pragma unroll
      for (int ni = 0; ni < 2; ni++) {
        int n = ns + ni * 16 + lr;
        float bb = bias[n];
#pragma unroll
        for (int jj = 0; jj < 4; jj++) {
          int m = ms + mf * 16 + kg * 4 + jj;
          if (m < mEnd && m >= storeLo && !(m >= skipLo && m < skipHi))
            outp[(size_t)m * cV + n] = acc[mf][ni][jj] + bb;
        }
      }
    }
  }
}

// ---- row log-softmax, 2-pass online (read, read+write) ----
__global__ __launch_bounds__(256) void k_lsm(float* __restrict__ outp) {
  __shared__ float wm_[4], ws_[4];
  __shared__ float blz;
  int m = blockIdx.x;
  int tid = threadIdx.x, lane = tid & 63, wid = tid >> 6;
  float4* rp4 = (float4*)(outp + (size_t)m * cV);
  float mx = -INFINITY, sm = 0.f;
  for (int n = tid; n < cV / 4; n += 256) {
    float4 v = rp4[n];
    float lm = fmaxf(fmaxf(v.x, v.y), fmaxf(v.z, v.w));
    float nm = fmaxf(mx, lm);
    sm = sm * expf(mx - nm) + expf(v.x - nm) + expf(v.y - nm) + expf(v.z - nm) + expf(v.w - nm);
    mx = nm;
  }
#pragma unroll
  for (int off = 32; off >= 1; off >>= 1) {
    float om = __shfl_xor(mx, off), os = __shfl_xor(sm, off);
    float nm = fmaxf(mx, om);
    sm = sm * expf(mx - nm) + os * expf(om - nm);
    mx = nm;
  }
  if (lane == 0) { wm_[wid] = mx; ws_[wid] = sm; }
  __syncthreads();
  if (tid == 0) {
    float M = fmaxf(fmaxf(wm_[0], wm_[1]), fmaxf(wm_[2], wm_[3]));
    float S = ws_[0] * expf(wm_[0] - M) + ws_[1] * expf(wm_[1] - M) +
              ws_[2] * expf(wm_[2] - M) + ws_[3] * expf(wm_[3] - M);
    blz = M + logf(S);
  }
  __syncthreads();
  float lz = blz;
  for (int n = tid; n < cV / 4; n += 256) {
    float4 v = rp4[n];
    v.x -= lz; v.y -= lz; v.z -= lz; v.w -= lz;
    rp4[n] = v;
  }
}

extern "C" void kernel_launch(void* const* d_in, const int* in_sizes, int n_in,
                              void* d_out, int out_size, void* d_ws, size_t ws_size,
                              hipStream_t stream) {
  (void)in_sizes; (void)n_in; (void)out_size; (void)ws_size;
  const int* enc_input  = (const int*)d_in[0];
  const int* dec_input  = (const int*)d_in[1];
  const int* length     = (const int*)d_in[2];
  const float* eps      = (const float*)d_in[3];
  const float* enc_emb  = (const float*)d_in[4];
  const float* enc_Wih  = (const float*)d_in[5];
  const float* enc_Whh  = (const float*)d_in[6];
  const float* enc_bih  = (const float*)d_in[7];
  const float* enc_bhh  = (const float*)d_in[8];
  const float* latent_W = (const float*)d_in[9];
  const float* latent_b = (const float*)d_in[10];
  const float* dec_emb  = (const float*)d_in[11];
  const float* attn_W   = (const float*)d_in[12];
  const float* attn_b   = (const float*)d_in[13];
  const float* comb_W   = (const float*)d_in[14];
  const float* comb_b   = (const float*)d_in[15];
  const float* dec_Wih  = (const float*)d_in[16];
  const float* dec_Whh  = (const float*)d_in[17];
  const float* dec_bih  = (const float*)d_in[18];
  const float* dec_bhh  = (const float*)d_in[19];
  const float* pri_W    = (const float*)d_in[20];
  const float* pri_b    = (const float*)d_in[21];
  const float* inf_W    = (const float*)d_in[22];
  const float* inf_b    = (const float*)d_in[23];
  const float* aux_W    = (const float*)d_in[24];
  const float* aux_b    = (const float*)d_in[25];
  const float* out_W    = (const float*)d_in[26];
  const float* out_b    = (const float*)d_in[27];
  float* outp = (float*)d_out;
  float* outF = outp;

  // ---- scratch layout in logp head (all dead before k_logit2) ----
  size_t off = 0;
  float* c_enc = outF + off; off += 65536;
  float* c_dec = outF + off; off += 65536;
  float* scal  = outF + off; off += 4;
  off += 60;
  u16* HencZ = (u16*)(outF + off); off += 32768;
  u16* Hh    = (u16*)(outF + off); off += 66 * 32768;
  size_t zeroSpan = 196672;
  u16* encO  = (u16*)(outF + off); off += 2097152;
  u16* Xenc  = (u16*)(outF + off); off += 1048576;
  u16* Xdec  = (u16*)(outF + off); off += 1064960;
  u16* zbuf  = (u16*)(outF + off); off += 4096;
  float* mulv  = outF + off; off += 16384;
  float* biasE = outF + off; off += 4096;
  float* biasD = outF + off; off += 4096;
  float* tmp1  = outF + off; off += 1024;
  float* u0    = outF + off; off += 1024;
  float* WcxT  = outF + off; off += 524288;
  float* WczT  = outF + off; off += 131072;
  float* wPmT  = outF + off; off += 131072;
  float* auxWT = outF + off; off += 131072;
  float* M1    = outF + off; off += 131072;
  float* WfT   = outF + off; off += 1048576;
  u16* WhhEp = (u16*)(outF + off); off += 2097152;
  u16* Wbig  = (u16*)(outF + off); off += 2097152;
  u16* C1    = (u16*)(outF + off); off += 1048576;
  u16* C2    = (u16*)(outF + off); off += 262144;
  u16* Genc  = (u16*)(outF + off); off += 8388608;
  u16* Gdec  = (u16*)(outF + off); off += 8519680;
  float* priH = outF + off; off += 1064960;
  float* infH = outF + off; off += 1064960;
  float* S    = outF + off; off += 266240;
  u16* ctxH  = (u16*)(outF + off); off += 2129920;
  u16* auxH  = (u16*)(outF + off); off += 2129920;  // ends ~37.73M < WBOUT_OFF
  u16* WbOut = (u16*)(outF + WBOUT_OFF);            // logp rows [1200,1712)
  u16* Amat = (u16*)(outF + AMAT_OFF);              // logp tail
  u16* wsA = (u16*)d_ws;

  // ---- prep ----
  k_cvt<<<2048, 256, 0, stream>>>(out_W, WbOut, cV * cH);
  k_tr<<<dim3(16, 32), 256, 0, stream>>>(comb_W, 1792, 1024, WcxT);
  k_tr<<<dim3(4, 32), 256, 0, stream>>>(comb_W + 1664, 1792, 1024, WczT);
  k_tr<<<dim3(32, 4), 256, 0, stream>>>(pri_W, 1024, 128, wPmT);
  k_tr<<<dim3(4, 32), 256, 0, stream>>>(aux_W, 128, 1024, auxWT);
  k_gemv<<<4, 256, 0, stream>>>(aux_W, 128, pri_b, aux_b, tmp1, 128, 0);
  k_gemv<<<4, 256, 0, stream>>>(comb_W + 512, 1792, tmp1, comb_b, u0, 1024, 0);
  k_gemv<<<4, 256, 0, stream>>>(comb_W + 1536, 1792, pri_b, nullptr, u0, 128, 1);
  k_biasE<<<16, 256, 0, stream>>>(enc_bih, enc_bhh, biasE);
  k_biasD<<<16, 256, 0, stream>>>(dec_bih, dec_bhh, dec_Wih, u0, biasD);
  k_permW<<<4096, 256, 0, stream>>>(enc_Whh, WhhEp);
  k_gather<<<cT * cB, 256, 0, stream>>>(enc_input, enc_emb, Xenc, cT);
  k_gather<<<cTP1 * cB, 256, 0, stream>>>(dec_input, dec_emb, Xdec, cTP1);
  k_zero<<<(int)((zeroSpan + 255) / 256), 256, 0, stream>>>(c_enc, (int)zeroSpan);

  // ---- weight composition ----
  k_gemm<float, float, float, 0, 0, false><<<dim3(8, 16), 64, 0, stream>>>(
      comb_W + 512, 1792, auxWT, 1024, nullptr, comb_W + 1536, 1792, M1, 128, 1024);
  k_gemm<float, float, float, 0, 0, false><<<dim3(64, 16), 64, 0, stream>>>(
      wPmT, 128, M1, 128, nullptr, nullptr, 0, WfT, 1024, 128);
  k_gemm<float, float, u16, 1, 0, false><<<dim3(64, 64), 64, 0, stream>>>(
      dec_Wih, 1024, WfT, 1024, nullptr, dec_Whh, 1024, Wbig, 1024, 1024);
  k_gemm<float, float, u16, 1, 0, false><<<dim3(32, 64), 64, 0, stream>>>(
      dec_Wih, 1024, WcxT, 1024, nullptr, nullptr, 0, C1, 512, 1024);
  k_gemm<float, float, u16, 1, 0, false><<<dim3(8, 64), 64, 0, stream>>>(
      dec_Wih, 1024, WczT, 1024, nullptr, nullptr, 0, C2, 128, 1024);
  k_gemm<u16, float, u16, 0, 1, false><<<dim3(256, 64), 64, 0, stream>>>(
      Xenc, 512, enc_Wih, 512, biasE, nullptr, 0, Genc, 4096, 512);

  // ---- encoder loop ----
  for (int t = 0; t < cT; t++) {
    const u16* Hcur = t ? (encO + (size_t)(t - 1) * cH) : HencZ;
    int sH = t ? (cT * cH) : cH;
    k_cell2<<<256, 64, 0, stream>>>(Genc + (size_t)t * cB * 4096, Hcur, sH, WhhEp,
                                    c_enc, encO + (size_t)t * cH, cT * cH, nullptr, 0);
  }
  k_latent<<<cB, 256, 0, stream>>>(encO, c_enc, latent_W, latent_b, mulv, outp);
  k_z<<<(cB * cZ + 255) / 256, 256, 0, stream>>>(mulv, eps, zbuf);

  // ---- Gdec ----
  k_gemm<u16, u16, u16, 0, 0, false><<<dim3(256, 65), 64, 0, stream>>>(
      Xdec, 512, C1, 512, biasD, nullptr, 0, Gdec, 4096, 512);
  k_gemm<u16, u16, u16, 2, 0, true><<<dim3(256, 65), 64, 0, stream>>>(
      zbuf, 128, C2, 128, nullptr, nullptr, 0, Gdec, 4096, 128);

  // ---- decoder loop ----
  for (int t = 0; t < cTP1; t++) {
    k_cell2<<<256, 64, 0, stream>>>(Gdec + (size_t)t * cB * 4096,
                                    Hh + (size_t)t * cB * cH, cH, Wbig, c_dec,
                                    Hh + (size_t)(t + 1) * cB * cH, cH,
                                    Amat + (size_t)t * cH, (long long)cTP1 * cH);
  }

  // ---- post-hoc batched math ----
  k_gemm<u16, float, float, 0, 0, false><<<dim3(16, 65), 64, 0, stream>>>(
      Hh, 1024, pri_W, 1024, pri_b, nullptr, 0, priH, 256, 1024);
  k_gemm<u16, float, float, 0, 0, false><<<dim3(4, 65), 64, 0, stream>>>(
      Xdec, 512, attn_W, 1536, attn_b, nullptr, 0, S, 64, 512);
  k_gemm<u16, float, float, 0, 0, true><<<dim3(4, 65), 64, 0, stream>>>(
      Hh, 1024, attn_W + 512, 1536, nullptr, nullptr, 0, S, 64, 1024);
  k_sctx<<<cTP1 * cB, 256, 0, stream>>>(S, enc_input, encO, ctxH);
  k_gemm<u16, float, float, 0, 0, false><<<dim3(16, 65), 64, 0, stream>>>(
      Hh, 1024, inf_W, 2048, inf_b, nullptr, 0, infH, 256, 1024);
  k_gemm<u16, float, float, 0, 0, true><<<dim3(16, 65), 64, 0, stream>>>(
      ctxH, 1024, inf_W + 1024, 2048, nullptr, nullptr, 0, infH, 256, 1024);
  k_gemm<float, float, u16, 0, 0, false><<<dim3(64, 65), 64, 0, stream>>>(
      priH, 256, aux_W, 128, aux_b, nullptr, 0, auxH, 1024, 128);
  k_scal_all<<<cTP1 * cB, 256, 0, stream>>>(priH, infH, ctxH, auxH, length, scal);
  k_scal<<<1, 64, 0, stream>>>(scal, outp);

  // ---- output projection (LDS W panel) + log-softmax ----
  k_cpyA<<<64, 256, 0, stream>>>(Amat, wsA);
  // L1: rows [0,4093) from Amat, W from bf16 panel; skip the panel's own rows
  k_logit2<u16><<<500, 512, 131072, stream>>>(Amat, 0, WbOut, out_b, outp,
                                              0, 4093, SKIP_LO, SKIP_HI, 0);
  // L2a: fill the skipped stripe, W streamed from f32 original
  k_logit2<float><<<500, 512, 131072, stream>>>(Amat, 0, out_W, out_b, outp,
                                                SKIP_LO, SKIP_HI, 0, 0, 0);
  // L2b: tail rows from the d_ws A-copy
  k_logit2<float><<<500, 512, 131072, stream>>>(wsA, 4032, out_W, out_b, outp,
                                                4032, 4160, 0, 0, 4093);
  k_lsm<<<cB * cTP1, 256, 0, stream>>>(outp);
}

// Round 10
// 4017.424 us; speedup vs baseline: 11.4109x; 1.1998x over previous
//
#include <hip/hip_runtime.h>
#include <hip/hip_bf16.h>
#include <cmath>

typedef unsigned short u16;
typedef __attribute__((ext_vector_type(8))) short short8;
typedef __attribute__((ext_vector_type(4))) float floatx4;

#define DEVI __device__ __forceinline__

constexpr int cV = 32000, cE = 512, cT = 64, cH = 1024, cZ = 128, cB = 64, cPAD = 31999, cTP1 = 65;
constexpr long long LOGP_SZ = 133120000LL;   // B*(T+1)*V f32 elems
constexpr long long AMAT_OFF = 130990080LL;  // logp tail: 260*32*512 u16 = 2,129,920 f32
constexpr long long WBOUT_OFF = 38400000LL;  // logp rows [1200,1712): 2000*32*512 u16
constexpr int SKIP_LO = 1200, SKIP_HI = 1712;

DEVI float b2f(u16 u) { return __uint_as_float(((unsigned)u) << 16); }
DEVI u16 f2b(float f) {
  unsigned u = __float_as_uint(f);
  unsigned r = u + 0x7FFFu + ((u >> 16) & 1u);
  return (u16)(r >> 16);
}
DEVI unsigned pk2(float lo, float hi) {
  __hip_bfloat162 t = __float22bfloat162_rn(make_float2(lo, hi));
  return *reinterpret_cast<unsigned*>(&t);
}
DEVI float sigm(float x) { return 1.f / (1.f + expf(-x)); }

DEVI short8 ldfragW(const float* __restrict__ p) {
  float4 x = *(const float4*)p, y = *(const float4*)(p + 4);
  union { unsigned u[4]; short8 s; } r;
  r.u[0] = pk2(x.x, x.y); r.u[1] = pk2(x.z, x.w);
  r.u[2] = pk2(y.x, y.y); r.u[3] = pk2(y.z, y.w);
  return r.s;
}

template <typename T>
DEVI short8 ldfrag(const T* __restrict__ p) {
  if constexpr (sizeof(T) == 2) return *(const short8*)(p);
  else return ldfragW((const float*)p);
}

template <int MAP>
DEVI int rmap(int r) {
  if constexpr (MAP == 1) return ((r & 3) << 10) | (r >> 2);
  else if constexpr (MAP == 2) return r & 63;
  else return r;
}

DEVI float dot_wf(const float* __restrict__ w, const float* __restrict__ s, int K) {
  float a0 = 0.f, a1 = 0.f, a2 = 0.f, a3 = 0.f;
#pragma unroll 4
  for (int k = 0; k < K; k += 8) {
    float4 p = *(const float4*)(w + k);
    float4 q = *(const float4*)(w + k + 4);
    a0 = fmaf(s[k + 0], p.x, a0); a1 = fmaf(s[k + 1], p.y, a1);
    a2 = fmaf(s[k + 2], p.z, a2); a3 = fmaf(s[k + 3], p.w, a3);
    a0 = fmaf(s[k + 4], q.x, a0); a1 = fmaf(s[k + 5], q.y, a1);
    a2 = fmaf(s[k + 6], q.z, a2); a3 = fmaf(s[k + 7], q.w, a3);
  }
  return (a0 + a1) + (a2 + a3);
}

__global__ __launch_bounds__(256) void k_zero(float* p, int n) {
  int i = blockIdx.x * 256 + threadIdx.x;
  if (i < n) p[i] = 0.f;
}

// ---------- generic MFMA GEMM (prep/post-hoc paths, proven) ----------
template <typename AT, typename BT, typename CT, int AMAP, int BMAP, bool ADDC>
__global__ __launch_bounds__(64) void k_gemm(
    const AT* __restrict__ A, int lda, const BT* __restrict__ B, int ldb,
    const float* __restrict__ bias, const float* __restrict__ Dm, int ldd,
    CT* __restrict__ C, int ldc, int K) {
  int nblk = blockIdx.x, mblk = blockIdx.y;
  int lane = threadIdx.x;
  int lr = lane & 15, kg = lane >> 4;
  const BT* Bp = B + (size_t)rmap<BMAP>(nblk * 16 + lr) * ldb + kg * 8;
  const AT* Ap[4];
#pragma unroll
  for (int mf = 0; mf < 4; mf++)
    Ap[mf] = A + (size_t)rmap<AMAP>(mblk * 64 + mf * 16 + lr) * lda + kg * 8;
  floatx4 acc[4];
#pragma unroll
  for (int mf = 0; mf < 4; mf++) acc[mf] = (floatx4){0.f, 0.f, 0.f, 0.f};
#pragma unroll 4
  for (int ks = 0; ks < K / 32; ks++) {
    short8 bv = ldfrag(Bp + ks * 32);
#pragma unroll
    for (int mf = 0; mf < 4; mf++) {
      short8 av = ldfrag(Ap[mf] + ks * 32);
      acc[mf] = __builtin_amdgcn_mfma_f32_16x16x32_bf16(av, bv, acc[mf], 0, 0, 0);
    }
  }
  int n = nblk * 16 + lr;
  float bs = bias ? bias[n] : 0.f;
#pragma unroll
  for (int mf = 0; mf < 4; mf++) {
#pragma unroll
    for (int jj = 0; jj < 4; jj++) {
      int m = mblk * 64 + mf * 16 + kg * 4 + jj;
      size_t ci = (size_t)m * ldc + n;
      float v = acc[mf][jj] + bs;
      if (Dm) v += Dm[(size_t)rmap<AMAP>(m) * ldd + n];
      if constexpr (ADDC) {
        if constexpr (sizeof(CT) == 2) v += b2f(C[ci]);
        else v += C[ci];
      }
      if constexpr (sizeof(CT) == 2) C[ci] = f2b(v);
      else C[ci] = v;
    }
  }
}

// ---------- serial step: gates = G[t] + Wbig x h; LSTM cell; frag-scatter h ----------
__global__ __launch_bounds__(64) void k_cell2(
    const u16* __restrict__ G, const u16* __restrict__ H, int strideH,
    const u16* __restrict__ Wb, float* __restrict__ c,
    u16* __restrict__ out1, int s1, u16* __restrict__ Afrag, int t) {
  int nb = blockIdx.x;
  int lane = threadIdx.x;
  int lr = lane & 15, kg = lane >> 4;
  const u16* Bp = Wb + (size_t)(nb * 16 + lr) * cH + kg * 8;
  floatx4 acc[4];
#pragma unroll
  for (int mf = 0; mf < 4; mf++) acc[mf] = (floatx4){0.f, 0.f, 0.f, 0.f};
#pragma unroll 8
  for (int ks = 0; ks < 32; ks++) {
    short8 bv = *(const short8*)(Bp + ks * 32);
#pragma unroll
    for (int mf = 0; mf < 4; mf++) {
      short8 av = *(const short8*)(H + (size_t)(mf * 16 + lr) * strideH + ks * 32 + kg * 8);
      acc[mf] = __builtin_amdgcn_mfma_f32_16x16x32_bf16(av, bv, acc[mf], 0, 0, 0);
    }
  }
  __shared__ float lds[16][65];
#pragma unroll
  for (int mf = 0; mf < 4; mf++)
#pragma unroll
    for (int jj = 0; jj < 4; jj++)
      lds[lr][mf * 16 + kg * 4 + jj] = acc[mf][jj];
  __syncthreads();
#pragma unroll
  for (int a = 0; a < 4; a++) {
    int b = lane;
    int j = nb * 4 + a;
    ushort4 gv = *(const ushort4*)(G + (size_t)b * 4096 + nb * 16 + 4 * a);
    float gi = lds[4 * a + 0][b] + b2f(gv.x);
    float gf = lds[4 * a + 1][b] + b2f(gv.y);
    float gg = lds[4 * a + 2][b] + b2f(gv.z);
    float go = lds[4 * a + 3][b] + b2f(gv.w);
    int ci = b * cH + j;
    float cc = c[ci];
    cc = sigm(gf) * cc + sigm(gi) * tanhf(gg);
    float hh = sigm(go) * tanhf(cc);
    c[ci] = cc;
    u16 hb = f2b(hh);
    out1[(size_t)b * s1 + j] = hb;
    if (Afrag) {
      int m = b * cTP1 + t;
      size_t idx = ((size_t)(m >> 4) * 32 + (j >> 5)) * 512 +
                   ((((j >> 3) & 3) * 16) + (m & 15)) * 8 + (j & 7);
      Afrag[idx] = hb;
    }
  }
}

// ---------- small prep kernels ----------
__global__ __launch_bounds__(256) void k_tr(const float* __restrict__ src, int ld,
                                            int R, float* __restrict__ dst) {
  __shared__ float tile[32][33];
  int c0 = blockIdx.x * 32, r0 = blockIdx.y * 32;
  int tx = threadIdx.x & 31, ty = threadIdx.x >> 5;
  for (int i = ty; i < 32; i += 8) tile[i][tx] = src[(size_t)(r0 + i) * ld + c0 + tx];
  __syncthreads();
  for (int i = ty; i < 32; i += 8) dst[(size_t)(c0 + i) * R + r0 + tx] = tile[tx][i];
}

__global__ __launch_bounds__(256) void k_gemv(const float* __restrict__ W, int ld,
                                              const float* __restrict__ x,
                                              const float* __restrict__ b,
                                              float* __restrict__ out, int K, int add) {
  int n = blockIdx.x * 256 + threadIdx.x;
  const float* w = W + (size_t)n * ld;
  float s = b ? b[n] : 0.f;
  for (int k = 0; k < K; k += 4) {
    float4 wv = *(const float4*)(w + k);
    float4 xv = *(const float4*)(x + k);
    s += wv.x * xv.x + wv.y * xv.y + wv.z * xv.z + wv.w * xv.w;
  }
  if (add) out[n] += s; else out[n] = s;
}

__global__ __launch_bounds__(256) void k_biasD(const float* __restrict__ bih,
                                               const float* __restrict__ bhh,
                                               const float* __restrict__ Wih,
                                               const float* __restrict__ u0,
                                               float* __restrict__ biasD) {
  int np = blockIdx.x * 256 + threadIdx.x;
  int src = ((np & 3) << 10) | (np >> 2);
  const float* w = Wih + (size_t)src * cH;
  float s = bih[src] + bhh[src];
  for (int k = 0; k < cH; k += 4) {
    float4 wv = *(const float4*)(w + k);
    float4 xv = *(const float4*)(u0 + k);
    s += wv.x * xv.x + wv.y * xv.y + wv.z * xv.z + wv.w * xv.w;
  }
  biasD[np] = s;
}

__global__ __launch_bounds__(256) void k_biasE(const float* __restrict__ bih,
                                               const float* __restrict__ bhh,
                                               float* __restrict__ biasE) {
  int np = blockIdx.x * 256 + threadIdx.x;
  int src = ((np & 3) << 10) | (np >> 2);
  biasE[np] = bih[src] + bhh[src];
}

__global__ __launch_bounds__(256) void k_permW(const float* __restrict__ Whh,
                                               u16* __restrict__ Wp) {
  int np = blockIdx.x;
  int src = ((np & 3) << 10) | (np >> 2);
  const float* w = Whh + (size_t)src * cH;
  u16* d = Wp + (size_t)np * cH;
  int tid = threadIdx.x;
#pragma unroll
  for (int p = 0; p < 4; p++) d[tid + p * 256] = f2b(w[tid + p * 256]);
}

// out_W (f32 row-major) -> frag-linear bf16: one wave per 16x32 frag
__global__ __launch_bounds__(256) void k_cvtW(const float* __restrict__ W,
                                              u16* __restrict__ Wf) {
  int g = blockIdx.x * 4 + (threadIdx.x >> 6);  // frag id 0..63999
  int l = threadIdx.x & 63;
  int nblk = g >> 5, kb = g & 31;
  const float* src = W + (size_t)(nblk * 16 + (l & 15)) * cH + kb * 32 + (l >> 4) * 8;
  *(short8*)(Wf + (size_t)g * 512 + l * 8) = ldfragW(src);
}

__global__ __launch_bounds__(256) void k_gather(const int* __restrict__ tok,
                                                const float* __restrict__ emb,
                                                u16* __restrict__ dst, int Tlen) {
  int r = blockIdx.x;
  int t = r >> 6, b = r & 63;
  const float* src = emb + (size_t)tok[b * Tlen + t] * cE;
  u16* d = dst + (size_t)r * cE;
  int tid = threadIdx.x;
  for (int k = tid; k < cE; k += 256) d[k] = f2b(src[k]);
}

// ---------- latent / z ----------
__global__ __launch_bounds__(256) void k_latent(
    const u16* __restrict__ encO, const float* __restrict__ cT2,
    const float* __restrict__ W, const float* __restrict__ bias,
    float* __restrict__ mulv, float* __restrict__ outp) {
  __shared__ float s[2 * cH];
  int b = blockIdx.x;
  int n = threadIdx.x;
  for (int k = n; k < cH; k += 256) {
    s[k] = b2f(encO[((size_t)b * cT + 63) * cH + k]);
    s[cH + k] = cT2[b * cH + k];
  }
  __syncthreads();
  float acc = bias[n] + dot_wf(W + (size_t)n * (2 * cH), s, 2 * cH);
  mulv[b * 256 + n] = acc;
  if (n < cZ)
    outp[LOGP_SZ + (size_t)b * cZ + n] = acc;
  else
    outp[LOGP_SZ + (size_t)cB * cZ + (size_t)b * cZ + (n - cZ)] = acc;
}

__global__ __launch_bounds__(256) void k_z(const float* __restrict__ mulv,
                                           const float* __restrict__ eps,
                                           u16* __restrict__ zbuf) {
  int i = blockIdx.x * 256 + threadIdx.x;
  if (i >= cB * cZ) return;
  int b = i >> 7, zi = i & 127;
  float mu = mulv[b * 256 + zi], lv = mulv[b * 256 + cZ + zi];
  zbuf[i] = f2b(mu + expf(0.5f * lv) * eps[i]);
}

// ---------- post-hoc: softmax + ctx ----------
__global__ __launch_bounds__(256) void k_sctx(
    const float* __restrict__ S, const int* __restrict__ enc_input,
    const u16* __restrict__ encO, u16* __restrict__ ctxH) {
  __shared__ float wat[cT];
  int tb = blockIdx.x;
  int b = tb & 63;
  int tid = threadIdx.x;
  if (tid < cT) {
    float sc = S[(size_t)tb * cT + tid];
    if (enc_input[b * cT + tid] == cPAD) sc = -INFINITY;
    float m = sc;
#pragma unroll
    for (int off = 32; off >= 1; off >>= 1) m = fmaxf(m, __shfl_xor(m, off));
    float p = expf(sc - m);
    float ssum = p;
#pragma unroll
    for (int off = 32; off >= 1; off >>= 1) ssum += __shfl_xor(ssum, off);
    wat[tid] = p / ssum;
  }
  __syncthreads();
#pragma unroll
  for (int p = 0; p < 4; p++) {
    int j = tid + p * 256;
    float s = 0.f;
    const u16* e = encO + ((size_t)b * cT) * cH + j;
#pragma unroll 8
    for (int t2 = 0; t2 < cT; t2++) s += wat[t2] * b2f(e[(size_t)t2 * cH]);
    ctxH[(size_t)tb * cH + j] = f2b(s);
  }
}

// ---------- post-hoc: kld + aux_c reductions ----------
__global__ __launch_bounds__(256) void k_scal_all(
    const float* __restrict__ priH, const float* __restrict__ infH,
    const u16* __restrict__ ctxH, const u16* __restrict__ auxH,
    const int* __restrict__ length, float* __restrict__ scal) {
  __shared__ float red[256];
  int tb = blockIdx.x;
  int t = tb >> 6, b = tb & 63;
  int tid = threadIdx.x;
  float r = 0.f;
  if (tid < cZ) {
    float pm = priH[(size_t)tb * 256 + tid], plv = priH[(size_t)tb * 256 + cZ + tid];
    float im = infH[(size_t)tb * 256 + tid], ilv = infH[(size_t)tb * 256 + cZ + tid];
    float d = im - pm;
    r = plv - ilv + expf(ilv - plv) + d * d * expf(-plv) - 1.f;
  }
  red[tid] = r;
  __syncthreads();
  for (int sft = 128; sft > 0; sft >>= 1) {
    if (tid < sft) red[tid] += red[tid + sft];
    __syncthreads();
  }
  if (tid == 0 && (length[b] + 1 > t)) atomicAdd(&scal[0], 0.5f * red[0]);
  __syncthreads();
  float r2 = 0.f;
#pragma unroll
  for (int p = 0; p < 4; p++) {
    int j = tid + p * 256;
    float d = b2f(ctxH[(size_t)tb * cH + j]) - b2f(auxH[(size_t)tb * cH + j]);
    r2 += d * d;
  }
  red[tid] = r2;
  __syncthreads();
  for (int sft = 128; sft > 0; sft >>= 1) {
    if (tid < sft) red[tid] += red[tid + sft];
    __syncthreads();
  }
  if (tid == 0) atomicAdd(&scal[1], red[0]);
}

__global__ void k_scal(const float* __restrict__ scal, float* __restrict__ outp) {
  if (threadIdx.x == 0) {
    outp[LOGP_SZ + 2 * cB * cZ] = scal[0];
    outp[LOGP_SZ + 2 * cB * cZ + 1] = scal[1];
  }
}

// copy Amat frag m-blocks [252,260) (256 KB) into d_ws
__global__ __launch_bounds__(256) void k_cpyA(const u16* __restrict__ src,
                                              u16* __restrict__ dst) {
  int i = blockIdx.x * 256 + threadIdx.x;  // 8192 x uint4
  ((uint4*)dst)[i] = ((const uint4*)(src + (size_t)252 * 32 * 512))[i];
}

// ---- output projection v3: frag-linear A + 64KB frag W panel in LDS ----
// grid 1000 (N/32), 512 thr (8 waves); wave = 64 rows x 32 cols; m-iters of 512 rows.
template <bool WFRAG>
__global__ __launch_bounds__(512) void k_logit3(
    const u16* __restrict__ Af, int fragBase,
    const u16* __restrict__ Wf, const float* __restrict__ Wraw,
    const float* __restrict__ bias, float* __restrict__ outp,
    int mStart, int mEnd, int storeLo, int storeHi, int skipLo, int skipHi) {
  __shared__ u16 wpan[32768];  // [fr(2)][kblk(32)][512]
  int nb = blockIdx.x;
  int tid = threadIdx.x;
  if constexpr (WFRAG) {
    const uint4* src = (const uint4*)(Wf + (size_t)nb * 32768);
    uint4* dst = (uint4*)wpan;
#pragma unroll
    for (int q = 0; q < 8; q++) dst[tid + q * 512] = src[tid + q * 512];
  } else {
    int wv = tid >> 6, l = tid & 63;
    for (int f = wv; f < 64; f += 8) {
      int fr = f >> 5, kb = f & 31;
      const float* src = Wraw + (size_t)(nb * 32 + fr * 16 + (l & 15)) * cH + kb * 32 + (l >> 4) * 8;
      *(short8*)(wpan + f * 512 + l * 8) = ldfragW(src);
    }
  }
  __syncthreads();
  int wave = tid >> 6, lane = tid & 63;
  int lr = lane & 15, kg = lane >> 4;
  for (int m0 = mStart; m0 < mEnd; m0 += 512) {
    int mi = m0 + wave * 64;
    int mfg[4];
#pragma unroll
    for (int mf = 0; mf < 4; mf++) {
      int g = (mi >> 4) + mf;
      if (g > 259) g = 259;
      mfg[mf] = g - fragBase;
    }
    floatx4 acc[4][2];
#pragma unroll
    for (int mf = 0; mf < 4; mf++)
#pragma unroll
      for (int ni = 0; ni < 2; ni++) acc[mf][ni] = (floatx4){0.f, 0.f, 0.f, 0.f};
#pragma unroll 4
    for (int ks = 0; ks < 32; ks++) {
      short8 bv0 = *(const short8*)(wpan + ks * 512 + lane * 8);
      short8 bv1 = *(const short8*)(wpan + (32 + ks) * 512 + lane * 8);
#pragma unroll
      for (int mf = 0; mf < 4; mf++) {
        short8 av = *(const short8*)(Af + ((size_t)mfg[mf] * 32 + ks) * 512 + lane * 8);
        acc[mf][0] = __builtin_amdgcn_mfma_f32_16x16x32_bf16(av, bv0, acc[mf][0], 0, 0, 0);
        acc[mf][1] = __builtin_amdgcn_mfma_f32_16x16x32_bf16(av, bv1, acc[mf][1], 0, 0, 0);
      }
    }
#pragma unroll
    for (int mf = 0; mf < 4; mf++) {
#pragma unroll
      for (int ni = 0; ni < 2; ni++) {
        int n = nb * 32 + ni * 16 + lr;
        float bb = bias[n];
#pragma unroll
        for (int jj = 0; jj < 4; jj++) {
          int m = mi + mf * 16 + kg * 4 + jj;
          if (m >= storeLo && m < storeHi && !(m >= skipLo && m < skipHi))
            outp[(size_t)m * cV + n] = acc[mf][ni][jj] + bb;
        }
      }
    }
  }
}

// ---- row log-softmax, 2-pass online ----
__global__ __launch_bounds__(256) void k_lsm(float* __restrict__ outp) {
  __shared__ float wm_[4], ws_[4];
  __shared__ float blz;
  int m = blockIdx.x;
  int tid = threadIdx.x, lane = tid & 63, wid = tid >> 6;
  float4* rp4 = (float4*)(outp + (size_t)m * cV);
  float mx = -INFINITY, sm = 0.f;
  for (int n = tid; n < cV / 4; n += 256) {
    float4 v = rp4[n];
    float lm = fmaxf(fmaxf(v.x, v.y), fmaxf(v.z, v.w));
    float nm = fmaxf(mx, lm);
    sm = sm * expf(mx - nm) + expf(v.x - nm) + expf(v.y - nm) + expf(v.z - nm) + expf(v.w - nm);
    mx = nm;
  }
#pragma unroll
  for (int off = 32; off >= 1; off >>= 1) {
    float om = __shfl_xor(mx, off), os = __shfl_xor(sm, off);
    float nm = fmaxf(mx, om);
    sm = sm * expf(mx - nm) + os * expf(om - nm);
    mx = nm;
  }
  if (lane == 0) { wm_[wid] = mx; ws_[wid] = sm; }
  __syncthreads();
  if (tid == 0) {
    float M = fmaxf(fmaxf(wm_[0], wm_[1]), fmaxf(wm_[2], wm_[3]));
    float S = ws_[0] * expf(wm_[0] - M) + ws_[1] * expf(wm_[1] - M) +
              ws_[2] * expf(wm_[2] - M) + ws_[3] * expf(wm_[3] - M);
    blz = M + logf(S);
  }
  __syncthreads();
  float lz = blz;
  for (int n = tid; n < cV / 4; n += 256) {
    float4 v = rp4[n];
    v.x -= lz; v.y -= lz; v.z -= lz; v.w -= lz;
    rp4[n] = v;
  }
}

extern "C" void kernel_launch(void* const* d_in, const int* in_sizes, int n_in,
                              void* d_out, int out_size, void* d_ws, size_t ws_size,
                              hipStream_t stream) {
  (void)in_sizes; (void)n_in; (void)out_size; (void)ws_size;
  const int* enc_input  = (const int*)d_in[0];
  const int* dec_input  = (const int*)d_in[1];
  const int* length     = (const int*)d_in[2];
  const float* eps      = (const float*)d_in[3];
  const float* enc_emb  = (const float*)d_in[4];
  const float* enc_Wih  = (const float*)d_in[5];
  const float* enc_Whh  = (const float*)d_in[6];
  const float* enc_bih  = (const float*)d_in[7];
  const float* enc_bhh  = (const float*)d_in[8];
  const float* latent_W = (const float*)d_in[9];
  const float* latent_b = (const float*)d_in[10];
  const float* dec_emb  = (const float*)d_in[11];
  const float* attn_W   = (const float*)d_in[12];
  const float* attn_b   = (const float*)d_in[13];
  const float* comb_W   = (const float*)d_in[14];
  const float* comb_b   = (const float*)d_in[15];
  const float* dec_Wih  = (const float*)d_in[16];
  const float* dec_Whh  = (const float*)d_in[17];
  const float* dec_bih  = (const float*)d_in[18];
  const float* dec_bhh  = (const float*)d_in[19];
  const float* pri_W    = (const float*)d_in[20];
  const float* pri_b    = (const float*)d_in[21];
  const float* inf_W    = (const float*)d_in[22];
  const float* inf_b    = (const float*)d_in[23];
  const float* aux_W    = (const float*)d_in[24];
  const float* aux_b    = (const float*)d_in[25];
  const float* out_W    = (const float*)d_in[26];
  const float* out_b    = (const float*)d_in[27];
  float* outp = (float*)d_out;
  float* outF = outp;

  // ---- scratch layout in logp head (dead before k_logit3) ----
  size_t off = 0;
  float* c_enc = outF + off; off += 65536;
  float* c_dec = outF + off; off += 65536;
  float* scal  = outF + off; off += 4;
  off += 60;
  u16* HencZ = (u16*)(outF + off); off += 32768;
  u16* Hh    = (u16*)(outF + off); off += 66 * 32768;
  size_t zeroSpan = 196672;
  u16* encO  = (u16*)(outF + off); off += 2097152;
  u16* Xenc  = (u16*)(outF + off); off += 1048576;
  u16* Xdec  = (u16*)(outF + off); off += 1064960;
  u16* zbuf  = (u16*)(outF + off); off += 4096;
  float* mulv  = outF + off; off += 16384;
  float* biasE = outF + off; off += 4096;
  float* biasD = outF + off; off += 4096;
  float* tmp1  = outF + off; off += 1024;
  float* u0    = outF + off; off += 1024;
  float* WcxT  = outF + off; off += 524288;
  float* WczT  = outF + off; off += 131072;
  float* wPmT  = outF + off; off += 131072;
  float* auxWT = outF + off; off += 131072;
  float* M1    = outF + off; off += 131072;
  float* WfT   = outF + off; off += 1048576;
  u16* WhhEp = (u16*)(outF + off); off += 2097152;
  u16* Wbig  = (u16*)(outF + off); off += 2097152;
  u16* C1    = (u16*)(outF + off); off += 1048576;
  u16* C2    = (u16*)(outF + off); off += 262144;
  u16* Genc  = (u16*)(outF + off); off += 8388608;
  u16* Gdec  = (u16*)(outF + off); off += 8519680;
  float* priH = outF + off; off += 1064960;
  float* infH = outF + off; off += 1064960;
  float* S    = outF + off; off += 266240;
  u16* ctxH  = (u16*)(outF + off); off += 2129920;
  u16* auxH  = (u16*)(outF + off); off += 2129920;  // ends ~37.73M < WBOUT_OFF
  u16* Wf   = (u16*)(outF + WBOUT_OFF);   // frag bf16 out_W: logp rows [1200,1712)
  u16* Amat = (u16*)(outF + AMAT_OFF);    // frag bf16 A: logp tail
  u16* wsA = (u16*)d_ws;

  // ---- prep ----
  k_cvtW<<<16000, 256, 0, stream>>>(out_W, Wf);
  k_tr<<<dim3(16, 32), 256, 0, stream>>>(comb_W, 1792, 1024, WcxT);
  k_tr<<<dim3(4, 32), 256, 0, stream>>>(comb_W + 1664, 1792, 1024, WczT);
  k_tr<<<dim3(32, 4), 256, 0, stream>>>(pri_W, 1024, 128, wPmT);
  k_tr<<<dim3(4, 32), 256, 0, stream>>>(aux_W, 128, 1024, auxWT);
  k_gemv<<<4, 256, 0, stream>>>(aux_W, 128, pri_b, aux_b, tmp1, 128, 0);
  k_gemv<<<4, 256, 0, stream>>>(comb_W + 512, 1792, tmp1, comb_b, u0, 1024, 0);
  k_gemv<<<4, 256, 0, stream>>>(comb_W + 1536, 1792, pri_b, nullptr, u0, 128, 1);
  k_biasE<<<16, 256, 0, stream>>>(enc_bih, enc_bhh, biasE);
  k_biasD<<<16, 256, 0, stream>>>(dec_bih, dec_bhh, dec_Wih, u0, biasD);
  k_permW<<<4096, 256, 0, stream>>>(enc_Whh, WhhEp);
  k_gather<<<cT * cB, 256, 0, stream>>>(enc_input, enc_emb, Xenc, cT);
  k_gather<<<cTP1 * cB, 256, 0, stream>>>(dec_input, dec_emb, Xdec, cTP1);
  k_zero<<<(int)((zeroSpan + 255) / 256), 256, 0, stream>>>(c_enc, (int)zeroSpan);

  // ---- weight composition ----
  k_gemm<float, float, float, 0, 0, false><<<dim3(8, 16), 64, 0, stream>>>(
      comb_W + 512, 1792, auxWT, 1024, nullptr, comb_W + 1536, 1792, M1, 128, 1024);
  k_gemm<float, float, float, 0, 0, false><<<dim3(64, 16), 64, 0, stream>>>(
      wPmT, 128, M1, 128, nullptr, nullptr, 0, WfT, 1024, 128);
  k_gemm<float, float, u16, 1, 0, false><<<dim3(64, 64), 64, 0, stream>>>(
      dec_Wih, 1024, WfT, 1024, nullptr, dec_Whh, 1024, Wbig, 1024, 1024);
  k_gemm<float, float, u16, 1, 0, false><<<dim3(32, 64), 64, 0, stream>>>(
      dec_Wih, 1024, WcxT, 1024, nullptr, nullptr, 0, C1, 512, 1024);
  k_gemm<float, float, u16, 1, 0, false><<<dim3(8, 64), 64, 0, stream>>>(
      dec_Wih, 1024, WczT, 1024, nullptr, nullptr, 0, C2, 128, 1024);
  k_gemm<u16, float, u16, 0, 1, false><<<dim3(256, 64), 64, 0, stream>>>(
      Xenc, 512, enc_Wih, 512, biasE, nullptr, 0, Genc, 4096, 512);

  // ---- encoder loop ----
  for (int t = 0; t < cT; t++) {
    const u16* Hcur = t ? (encO + (size_t)(t - 1) * cH) : HencZ;
    int sH = t ? (cT * cH) : cH;
    k_cell2<<<256, 64, 0, stream>>>(Genc + (size_t)t * cB * 4096, Hcur, sH, WhhEp,
                                    c_enc, encO + (size_t)t * cH, cT * cH, nullptr, 0);
  }
  k_latent<<<cB, 256, 0, stream>>>(encO, c_enc, latent_W, latent_b, mulv, outp);
  k_z<<<(cB * cZ + 255) / 256, 256, 0, stream>>>(mulv, eps, zbuf);

  // ---- Gdec ----
  k_gemm<u16, u16, u16, 0, 0, false><<<dim3(256, 65), 64, 0, stream>>>(
      Xdec, 512, C1, 512, biasD, nullptr, 0, Gdec, 4096, 512);
  k_gemm<u16, u16, u16, 2, 0, true><<<dim3(256, 65), 64, 0, stream>>>(
      zbuf, 128, C2, 128, nullptr, nullptr, 0, Gdec, 4096, 128);

  // ---- decoder loop ----
  for (int t = 0; t < cTP1; t++) {
    k_cell2<<<256, 64, 0, stream>>>(Gdec + (size_t)t * cB * 4096,
                                    Hh + (size_t)t * cB * cH, cH, Wbig, c_dec,
                                    Hh + (size_t)(t + 1) * cB * cH, cH,
                                    Amat, t);
  }

  // ---- post-hoc batched math ----
  k_gemm<u16, float, float, 0, 0, false><<<dim3(16, 65), 64, 0, stream>>>(
      Hh, 1024, pri_W, 1024, pri_b, nullptr, 0, priH, 256, 1024);
  k_gemm<u16, float, float, 0, 0, false><<<dim3(4, 65), 64, 0, stream>>>(
      Xdec, 512, attn_W, 1536, attn_b, nullptr, 0, S, 64, 512);
  k_gemm<u16, float, float, 0, 0, true><<<dim3(4, 65), 64, 0, stream>>>(
      Hh, 1024, attn_W + 512, 1536, nullptr, nullptr, 0, S, 64, 1024);
  k_sctx<<<cTP1 * cB, 256, 0, stream>>>(S, enc_input, encO, ctxH);
  k_gemm<u16, float, float, 0, 0, false><<<dim3(16, 65), 64, 0, stream>>>(
      Hh, 1024, inf_W, 2048, inf_b, nullptr, 0, infH, 256, 1024);
  k_gemm<u16, float, float, 0, 0, true><<<dim3(16, 65), 64, 0, stream>>>(
      ctxH, 1024, inf_W + 1024, 2048, nullptr, nullptr, 0, infH, 256, 1024);
  k_gemm<float, float, u16, 0, 0, false><<<dim3(64, 65), 64, 0, stream>>>(
      priH, 256, aux_W, 128, aux_b, nullptr, 0, auxH, 1024, 128);
  k_scal_all<<<cTP1 * cB, 256, 0, stream>>>(priH, infH, ctxH, auxH, length, scal);
  k_scal<<<1, 64, 0, stream>>>(scal, outp);

  // ---- output projection + log-softmax ----
  k_cpyA<<<32, 256, 0, stream>>>(Amat, wsA);
  // L1: all rows, store m<4093 minus the Wf stripe; A frag, W frag panel
  k_logit3<true><<<1000, 512, 0, stream>>>(Amat, 0, Wf, nullptr, out_b, outp,
                                           0, 4096, 0, 4093, SKIP_LO, SKIP_HI);
  // L2a: the stripe rows, W from f32 (Wf being overwritten is only read pre-L2a)
  k_logit3<false><<<1000, 512, 0, stream>>>(Amat, 0, nullptr, out_W, out_b, outp,
                                            SKIP_LO, SKIP_HI, SKIP_LO, SKIP_HI, 0, 0);
  // L2b: tail rows from the d_ws frag copy (Amat region gets overwritten here)
  k_logit3<false><<<1000, 512, 0, stream>>>(wsA, 252, nullptr, out_W, out_b, outp,
                                            4032, 4160, 4093, 4160, 0, 0);
  k_lsm<<<cB * cTP1, 256, 0, stream>>>(outp);
}